// Round 6
// baseline (1034.381 us; speedup 1.0000x reference)
//
#include <hip/hip_runtime.h>
#include <cstdint>
#include <cstddef>

// Problem constants (reference: B=2,S=1024,HID=4096,H=32,D=128,KVH=8,EH=8,AH=256)
#define B_    2
#define S_    1024
#define HID_  4096
#define H_    32
#define D_    128
#define KVH_  8
#define EH_   8
#define AH_   256
#define NTOK  2048

typedef unsigned short u16;
typedef __attribute__((ext_vector_type(8))) short bf16x8;
typedef __attribute__((ext_vector_type(4))) float f32x4;
typedef const __attribute__((address_space(1))) void* gp_t;
typedef __attribute__((address_space(3))) void* lp_t;

__device__ __forceinline__ u16 f2bf(float f) {              // RNE f32->bf16
  unsigned u = __float_as_uint(f);
  return (u16)((u + 0x7FFF + ((u >> 16) & 1)) >> 16);
}
__device__ __forceinline__ float bf2f(u16 u) {
  return __uint_as_float((unsigned)u << 16);
}

// --------------- token-type scan: inv[] + counts (1 block) ---------------
// inv[t] = compact index within its type. cnt = {ntext, ntext_pad, nent,
// nent_pad, ceil128(nent*8), _}
__global__ __launch_bounds__(1024) void build_inv(
    const int* __restrict__ ttm, int* __restrict__ inv, int* __restrict__ cnt)
{
  __shared__ int a[NTOK], b[NTOK];
  const int t = threadIdx.x;
  for (int i = t; i < NTOK; i += 1024) a[i] = (ttm[i] != 1) ? 1 : 0;
  __syncthreads();
  int* src = a; int* dst = b;
  for (int off = 1; off < NTOK; off <<= 1) {
    for (int i = t; i < NTOK; i += 1024)
      dst[i] = src[i] + ((i >= off) ? src[i - off] : 0);
    __syncthreads();
    int* tmp = src; src = dst; dst = tmp;
  }
  for (int i = t; i < NTOK; i += 1024) {
    const int txt = (ttm[i] != 1);
    const int excl = src[i] - txt;
    inv[i] = txt ? excl : (i - excl);
  }
  if (t == 0) {
    const int ntext = src[NTOK - 1];
    const int nent = NTOK - ntext;
    cnt[0] = ntext;
    cnt[1] = (ntext + 127) & ~127;
    cnt[2] = nent;
    cnt[3] = (nent + 127) & ~127;
    cnt[4] = (nent * 8 + 127) & ~127;
  }
}

// --------------- gather inputs to per-type compact bf16 ---------------
__global__ __launch_bounds__(256) void gather_cast(
    const float* __restrict__ x_text, const float* __restrict__ x_ent,
    const int* __restrict__ ttm, const int* __restrict__ inv,
    u16* __restrict__ xt, u16* __restrict__ xe)
{
  const int tok = blockIdx.x;
  const int j = inv[tok];
  const int t = threadIdx.x;
  if (ttm[tok] != 1) {
    const float* src = x_text + (size_t)tok * HID_;
    u16* dst = xt + (size_t)j * HID_;
#pragma unroll
    for (int i = 0; i < 4; i++) {
      const int c = (i * 256 + t) * 4;
      const float4 v = *(const float4*)(src + c);
      ushort4 o; o.x = f2bf(v.x); o.y = f2bf(v.y); o.z = f2bf(v.z); o.w = f2bf(v.w);
      *(ushort4*)(dst + c) = o;
    }
  } else {
    const float* src = x_ent + (size_t)tok * 1024;
    u16* dst = xe + (size_t)j * 1024;
    const int c = t * 4;
    const float4 v = *(const float4*)(src + c);
    ushort4 o; o.x = f2bf(v.x); o.y = f2bf(v.y); o.z = f2bf(v.z); o.w = f2bf(v.w);
    *(ushort4*)(dst + c) = o;
  }
}

// ---------------- batched weight transpose+cast ----------------
struct TSeg { const float* W; u16* Wt; int K; int N; int blk0; };
struct TArgs { TSeg s[12]; int nseg; };

__global__ __launch_bounds__(256) void batch_transpose(TArgs args)
{
  int seg = 0;
#pragma unroll
  for (int i = 1; i < 12; i++)
    if (i < args.nseg && (int)blockIdx.x >= args.s[i].blk0) seg = i;
  const float* W = args.s[seg].W;
  u16* Wt = args.s[seg].Wt;
  const int K = args.s[seg].K, N = args.s[seg].N;
  const int local = blockIdx.x - args.s[seg].blk0;

  __shared__ float tle[32][33];
  const int tid = threadIdx.x;
  const int tx = tid & 31, ty = tid >> 5;
  const int nb = N >> 5;
  const int k0 = (local / nb) << 5;
  const int n0 = (local % nb) << 5;
#pragma unroll
  for (int r = 0; r < 32; r += 8)
    tle[ty + r][tx] = W[(size_t)(k0 + ty + r) * N + n0 + tx];
  __syncthreads();
#pragma unroll
  for (int r = 0; r < 32; r += 8)
    Wt[(size_t)(n0 + ty + r) * K + k0 + tx] = f2bf(tle[tx][ty + r]);
}

// ---- shared GEMM segment descriptor (tile size depends on kernel) ----
struct GSeg {
  const u16* A; const u16* Bt; const float* bias; u16* C;
  int N, K, act, astride, mlimIdx, blk0, nTM, nTN;
};
struct GArgs { GSeg s[4]; int nseg; };

// --------------------- batched bf16 MFMA GEMM, 128x128 tile ---------------------
// For small GEMMs (N<=256). m97 2-barrier K-loop. Segments concurrent: no
// output/input aliasing allowed within one dispatch (r4 lesson).
__global__ __launch_bounds__(256) void gemm_batch(GArgs ga, const int* __restrict__ cnt)
{
  int seg = 0;
#pragma unroll
  for (int i = 1; i < 4; i++)
    if (i < ga.nseg && (int)blockIdx.x >= ga.s[i].blk0) seg = i;
  const GSeg sg = ga.s[seg];
  const int local = (int)blockIdx.x - sg.blk0;
  const int nTM = sg.nTM, nTN = sg.nTN;
  const int nwg = nTM * nTN;
  if (local >= nwg) return;                       // segment padding

  // bijective XCD swizzle (m204) + column-major tile order + row-stride perm
  const int xcd = local & 7, lix = local >> 3;
  const int q = nwg >> 3, rr_ = nwg & 7;
  const int wgid = (xcd < rr_ ? xcd * (q + 1) : rr_ * (q + 1) + (xcd - rr_) * q) + lix;
  const int tcol = wgid / nTM;
  int trow = wgid - tcol * nTM;
  if ((nTM & 7) == 0) trow = ((trow & 7) * (nTM >> 3)) + (trow >> 3);
  const int m0 = trow << 7;
  if (sg.mlimIdx >= 0 && m0 >= cnt[sg.mlimIdx]) return;
  const int n0 = tcol << 7;

  const int N = sg.N, K = sg.K;
  const u16* __restrict__ A = sg.A;
  const u16* __restrict__ Bt = sg.Bt;

  __shared__ __align__(16) char AsB[8192];
  __shared__ __align__(16) char BsB[8192];

  const int tid = threadIdx.x;
  const int wave = tid >> 6, lane = tid & 63;
  const int wm = ((wave >> 1) << 6);
  const int wn = ((wave & 1) << 6);
  const int l16 = lane & 15, lg = lane >> 4;

  const int ofs0 = (wave * 2) * 1024;
  const int flat0 = ofs0 + lane * 16;
  const int flat1 = flat0 + 1024;
  const int g0 = flat0 >> 11, r0 = (flat0 & 2047) >> 4;
  const int g1 = flat1 >> 11, r1 = (flat1 & 2047) >> 4;

  auto arow = [&](int row) -> size_t {
    return sg.astride ? (size_t)(row >> 3) * sg.astride + (size_t)(row & 7) * K
                      : (size_t)row * K;
  };
  const u16* a0 = A + arow(m0 + r0) + g0 * 8;
  const u16* a1 = A + arow(m0 + r1) + g1 * 8;
  const u16* b0 = Bt + (size_t)(n0 + r0) * K + g0 * 8;
  const u16* b1 = Bt + (size_t)(n0 + r1) * K + g1 * 8;

  f32x4 acc[4][4];
#pragma unroll
  for (int i = 0; i < 4; i++)
#pragma unroll
    for (int j = 0; j < 4; j++) acc[i][j] = (f32x4)0.f;

  for (int k0 = 0; k0 < K; k0 += 32) {
    if (k0) __syncthreads();
    __builtin_amdgcn_global_load_lds((gp_t)a0, (lp_t)(AsB + ofs0),        16, 0, 0);
    __builtin_amdgcn_global_load_lds((gp_t)a1, (lp_t)(AsB + ofs0 + 1024), 16, 0, 0);
    __builtin_amdgcn_global_load_lds((gp_t)b0, (lp_t)(BsB + ofs0),        16, 0, 0);
    __builtin_amdgcn_global_load_lds((gp_t)b1, (lp_t)(BsB + ofs0 + 1024), 16, 0, 0);
    a0 += 32; a1 += 32; b0 += 32; b1 += 32;
    __syncthreads();

    bf16x8 af[4], bv[4];
#pragma unroll
    for (int i = 0; i < 4; i++)
      af[i] = *(const bf16x8*)(AsB + lg * 2048 + (wm + 16 * i + l16) * 16);
#pragma unroll
    for (int j = 0; j < 4; j++)
      bv[j] = *(const bf16x8*)(BsB + lg * 2048 + (wn + 16 * j + l16) * 16);
#pragma unroll
    for (int i = 0; i < 4; i++)
#pragma unroll
      for (int j = 0; j < 4; j++)
        acc[i][j] = __builtin_amdgcn_mfma_f32_16x16x32_bf16(af[i], bv[j], acc[i][j], 0, 0, 0);
  }

#pragma unroll
  for (int i = 0; i < 4; i++) {
#pragma unroll
    for (int r = 0; r < 4; r++) {
      const int row = m0 + wm + 16 * i + lg * 4 + r;
#pragma unroll
      for (int j = 0; j < 4; j++) {
        const int col = n0 + wn + 16 * j + l16;
        float c = acc[i][j][r];
        if (sg.bias) c += sg.bias[col];
        if (sg.act) c = 0.5f * c * (1.f + erff(c * 0.70710678118654752f));  // exact GELU
        sg.C[(size_t)row * N + col] = f2bf(c);
      }
    }
  }
}

// --------------------- batched bf16 MFMA GEMM, 256x256 tile ---------------------
// For the big GEMMs (QKV/entity-proj/wo_t). Rounds 0-5 established these are
// L3/fabric-BW-bound: 128^2 tiles amplify logical read traffic ~13x over
// compulsory (each A-panel read N/128 times, B-panel M/128 times) and every
// schedule variant saturates at the same ~5 TB/s. 256^2 halves the traffic.
// 512 threads = 8 waves, each owning a 128x64 sub-tile (acc[8][4] f32x4).
// Same 16x16x32 fragment layout and 2-barrier K-loop as the 128^2 path.
// LDS 32 KB: A tile [chunk(4)][row(256)][16B] at 0, B tile same at 16384.
__global__ __launch_bounds__(512) void gemm_batch256(GArgs ga, const int* __restrict__ cnt)
{
  int seg = 0;
#pragma unroll
  for (int i = 1; i < 4; i++)
    if (i < ga.nseg && (int)blockIdx.x >= ga.s[i].blk0) seg = i;
  const GSeg sg = ga.s[seg];
  const int local = (int)blockIdx.x - sg.blk0;
  const int nTM = sg.nTM, nTN = sg.nTN;
  const int nwg = nTM * nTN;
  if (local >= nwg) return;                       // segment padding

  const int xcd = local & 7, lix = local >> 3;
  const int q = nwg >> 3, rr_ = nwg & 7;
  const int wgid = (xcd < rr_ ? xcd * (q + 1) : rr_ * (q + 1) + (xcd - rr_) * q) + lix;
  const int tcol = wgid / nTM;
  int trow = wgid - tcol * nTM;
  if ((nTM & 7) == 0) trow = ((trow & 7) * (nTM >> 3)) + (trow >> 3);
  const int m0 = trow << 8;
  if (sg.mlimIdx >= 0 && m0 >= cnt[sg.mlimIdx]) return;
  const int n0 = tcol << 8;

  const int N = sg.N, K = sg.K;
  const u16* __restrict__ A = sg.A;
  const u16* __restrict__ Bt = sg.Bt;

  __shared__ __align__(16) char LDS[32768];       // A:[0,16K) B:[16K,32K)

  const int tid = threadIdx.x;
  const int wave = tid >> 6, lane = tid & 63;
  const int wm = (wave >> 2) << 7;                // 2 wave-rows of 128
  const int wn = (wave & 3) << 6;                 // 4 wave-cols of 64
  const int l16 = lane & 15, lg = lane >> 4;

  // staging: 4 rounds of 8 KB (512 thr x 16 B). rounds 0,1 -> A; 2,3 -> B.
  // flat(r) = tid*16 + (r&1)*8192; chunk = flat>>12, row = (flat>>4)&255.
  // LDS addr == flat (layout [chunk][row][16B]); wave-uniform dst base =
  // wave*1024 + (r&1)*8192 (lane*16 added by HW).
  const int fl0 = tid * 16, fl1 = tid * 16 + 8192;
  const int c0 = fl0 >> 12, w0 = (fl0 >> 4) & 255;
  const int c1 = fl1 >> 12, w1 = (fl1 >> 4) & 255;
  const u16* a0 = A + (size_t)(m0 + w0) * K + c0 * 8;
  const u16* a1 = A + (size_t)(m0 + w1) * K + c1 * 8;
  const u16* b0 = Bt + (size_t)(n0 + w0) * K + c0 * 8;
  const u16* b1 = Bt + (size_t)(n0 + w1) * K + c1 * 8;
  const int dst0 = wave * 1024, dst1 = wave * 1024 + 8192;

  f32x4 acc[8][4];
#pragma unroll
  for (int i = 0; i < 8; i++)
#pragma unroll
    for (int j = 0; j < 4; j++) acc[i][j] = (f32x4)0.f;

  for (int k0 = 0; k0 < K; k0 += 32) {
    if (k0) __syncthreads();
    __builtin_amdgcn_global_load_lds((gp_t)a0, (lp_t)(LDS + dst0),         16, 0, 0);
    __builtin_amdgcn_global_load_lds((gp_t)a1, (lp_t)(LDS + dst1),         16, 0, 0);
    __builtin_amdgcn_global_load_lds((gp_t)b0, (lp_t)(LDS + 16384 + dst0), 16, 0, 0);
    __builtin_amdgcn_global_load_lds((gp_t)b1, (lp_t)(LDS + 16384 + dst1), 16, 0, 0);
    a0 += 32; a1 += 32; b0 += 32; b1 += 32;
    __syncthreads();

    bf16x8 af[8], bv[4];
#pragma unroll
    for (int i = 0; i < 8; i++)
      af[i] = *(const bf16x8*)(LDS + lg * 4096 + (wm + 16 * i + l16) * 16);
#pragma unroll
    for (int j = 0; j < 4; j++)
      bv[j] = *(const bf16x8*)(LDS + 16384 + lg * 4096 + (wn + 16 * j + l16) * 16);
#pragma unroll
    for (int i = 0; i < 8; i++)
#pragma unroll
      for (int j = 0; j < 4; j++)
        acc[i][j] = __builtin_amdgcn_mfma_f32_16x16x32_bf16(af[i], bv[j], acc[i][j], 0, 0, 0);
  }

#pragma unroll
  for (int i = 0; i < 8; i++) {
#pragma unroll
    for (int r = 0; r < 4; r++) {
      const int row = m0 + wm + 16 * i + lg * 4 + r;
#pragma unroll
      for (int j = 0; j < 4; j++) {
        const int col = n0 + wn + 16 * j + l16;
        float c = acc[i][j][r];
        if (sg.bias) c += sg.bias[col];
        if (sg.act) c = 0.5f * c * (1.f + erff(c * 0.70710678118654752f));
        sg.C[(size_t)row * N + col] = f2bf(c);
      }
    }
  }
}

// ------------- select + RoPE -> bf16 Q (prescaled), bf16 K (full token index) -------------
__global__ __launch_bounds__(256) void select_rope_bf(
    const u16* __restrict__ qkv, const u16* __restrict__ qe,
    const u16* __restrict__ ke, u16* __restrict__ Qb, u16* __restrict__ Kb,
    const int* __restrict__ ttm, const int* __restrict__ inv,
    const int* __restrict__ pid)
{
  __shared__ float cs[64], sn[64];
  const int token = blockIdx.x;
  const bool is_e = (ttm[token] == 1);
  const int j = inv[token];
  const int t = threadIdx.x;
  if (t < 64) {
    const float pos = (float)pid[token];
    const float iv = __expf(-((float)(2 * t) * (1.f / 128.f)) * 9.210340371976184f);
    const float f = pos * iv;
    cs[t] = cosf(f); sn[t] = sinf(f);
  }
  __syncthreads();
  const float scale = 0.08838834764831845f;  // 1/sqrt(128) folded into Q
  const u16* qrow = qkv + (size_t)j * 6144;

  for (int it = t; it < H_ * 64; it += 256) {
    const int h = it >> 6, i = it & 63;
    float x1, x2;
    if (is_e) {
      const size_t eb = ((size_t)j * 8 + (h & 7)) * D_;
      x1 = bf2f(qe[eb + i]); x2 = bf2f(qe[eb + i + 64]);
    } else {
      x1 = bf2f(qrow[h * 128 + i]); x2 = bf2f(qrow[h * 128 + i + 64]);
    }
    const size_t base = ((size_t)token * H_ + h) * D_;
    Qb[base + i]      = f2bf((x1 * cs[i] - x2 * sn[i]) * scale);
    Qb[base + i + 64] = f2bf((x2 * cs[i] + x1 * sn[i]) * scale);
  }
  for (int it = t; it < KVH_ * 64; it += 256) {
    const int h = it >> 6, i = it & 63;
    float x1, x2;
    if (is_e) {
      const size_t eb = ((size_t)j * 8 + h) * D_;
      x1 = bf2f(ke[eb + i]); x2 = bf2f(ke[eb + i + 64]);
    } else {
      x1 = bf2f(qrow[4096 + h * 128 + i]); x2 = bf2f(qrow[4096 + h * 128 + i + 64]);
    }
    const size_t base = ((size_t)token * KVH_ + h) * D_;
    Kb[base + i]      = f2bf(x1 * cs[i] - x2 * sn[i]);
    Kb[base + i + 64] = f2bf(x2 * cs[i] + x1 * sn[i]);
  }
}

// ---------- V select + transpose: VT[b][hk][d][s] bf16 ----------
__global__ __launch_bounds__(256) void vtrans_kernel(
    const u16* __restrict__ qkv, const u16* __restrict__ ve,
    const int* __restrict__ ttm, const int* __restrict__ inv,
    u16* __restrict__ VTg)
{
  __shared__ float t[32][33];
  const int dt = blockIdx.x & 3;
  const int st = (blockIdx.x >> 2) & 31;
  const int hk = (blockIdx.x >> 7) & 7;
  const int b  = blockIdx.x >> 10;
  const int s0 = st * 32, d0 = dt * 32;
  const int tx = threadIdx.x & 31, ty = threadIdx.x >> 5;
#pragma unroll
  for (int i = 0; i < 4; i++) {
    const int r = ty + 8 * i;
    const int tok = b * S_ + s0 + r;
    const int j = inv[tok];
    t[r][tx] = (ttm[tok] == 1)
        ? bf2f(ve[((size_t)j * 8 + hk) * D_ + d0 + tx])
        : bf2f(qkv[(size_t)j * 6144 + 5120 + hk * 128 + d0 + tx]);
  }
  __syncthreads();
#pragma unroll
  for (int i = 0; i < 4; i++) {
    const int rr = ty + 8 * i;
    VTg[((size_t)(b * KVH_ + hk) * D_ + d0 + rr) * S_ + s0 + tx] = f2bf(t[tx][rr]);
  }
}

// ------------------- MFMA causal GQA flash attention (compact output) -------------------
__global__ __launch_bounds__(256) void attn_mfma(
    const u16* __restrict__ Qb, const u16* __restrict__ Kb,
    const u16* __restrict__ VTg, u16* __restrict__ O,
    const int* __restrict__ ttm, const int* __restrict__ inv,
    const int* __restrict__ cnt)
{
  __shared__ __align__(16) u16 Ks[16 * 64 * 8];
  __shared__ __align__(16) u16 VTs[8 * 128 * 8];
  __shared__ __align__(16) float Ps[4][16 * 68];

  const int tid = threadIdx.x;
  const int wave = tid >> 6, lane = tid & 63;
  const int l16 = lane & 15, lg = lane >> 4;

  const int qtile = 15 - (blockIdx.x & 15);
  const int h = (blockIdx.x >> 4) & (H_ - 1);
  const int b = blockIdx.x >> 9;
  const int q0 = qtile * 64;
  const int hk = h & 7;
  const int qw = q0 + 16 * wave;
  const int qmax = qw + 15;

  bf16x8 qf[4];
  {
    const u16* qrow = Qb + ((size_t)(b * S_ + qw + l16) * H_ + h) * D_;
#pragma unroll
    for (int c = 0; c < 4; c++)
      qf[c] = *(const bf16x8*)(qrow + c * 32 + lg * 8);
  }

  f32x4 o[8];
#pragma unroll
  for (int nt = 0; nt < 8; nt++) o[nt] = (f32x4)0.f;
  float mrun[4] = {-1e30f, -1e30f, -1e30f, -1e30f};
  float lrun[4] = {0.f, 0.f, 0.f, 0.f};

  const int ntiles = qtile + 1;
  for (int t = 0; t < ntiles; t++) {
    const int k0 = t * 64;
    if (t) __syncthreads();
#pragma unroll
    for (int i = 0; i < 4; i++) {
      const int idx = i * 256 + tid;
      const int g = idx >> 6, key = idx & 63;
      *(bf16x8*)(Ks + idx * 8) =
          *(const bf16x8*)(Kb + ((size_t)(b * S_ + k0 + key) * KVH_ + hk) * D_ + g * 8);
    }
#pragma unroll
    for (int i = 0; i < 4; i++) {
      const int idx = i * 256 + tid;
      const int kg = idx >> 7, d = idx & 127;
      *(bf16x8*)(VTs + idx * 8) =
          *(const bf16x8*)(VTg + ((size_t)(b * KVH_ + hk) * D_ + d) * S_ + k0 + kg * 8);
    }
    __syncthreads();

    if (k0 > qmax) continue;

    f32x4 s[4];
#pragma unroll
    for (int c = 0; c < 4; c++) s[c] = (f32x4)0.f;
#pragma unroll
    for (int c = 0; c < 4; c++)
#pragma unroll
      for (int dc = 0; dc < 4; dc++) {
        const bf16x8 kf = *(const bf16x8*)(Ks + ((dc * 4 + lg) * 64 + c * 16 + l16) * 8);
        s[c] = __builtin_amdgcn_mfma_f32_16x16x32_bf16(qf[dc], kf, s[c], 0, 0, 0);
      }

    float p[4][4], alpha[4];
#pragma unroll
    for (int r = 0; r < 4; r++) {
      const int qg = qw + lg * 4 + r;
      float sv[4], mx = -1e30f;
#pragma unroll
      for (int c = 0; c < 4; c++) {
        const int kg_ = k0 + c * 16 + l16;
        float v = (kg_ <= qg) ? s[c][r] : -1e30f;
        sv[c] = v;
        mx = fmaxf(mx, v);
      }
#pragma unroll
      for (int off = 1; off < 16; off <<= 1)
        mx = fmaxf(mx, __shfl_xor(mx, off));
      const float mn = fmaxf(mrun[r], mx);
      alpha[r] = __expf(mrun[r] - mn);
      mrun[r] = mn;
      float rs = 0.f;
#pragma unroll
      for (int c = 0; c < 4; c++) { p[c][r] = __expf(sv[c] - mn); rs += p[c][r]; }
#pragma unroll
      for (int off = 1; off < 16; off <<= 1)
        rs += __shfl_xor(rs, off);
      lrun[r] = lrun[r] * alpha[r] + rs;
    }
#pragma unroll
    for (int nt = 0; nt < 8; nt++)
#pragma unroll
      for (int r = 0; r < 4; r++) o[nt][r] *= alpha[r];

    float* pw = Ps[wave];
#pragma unroll
    for (int c = 0; c < 4; c++)
#pragma unroll
      for (int r = 0; r < 4; r++)
        pw[(lg * 4 + r) * 68 + c * 16 + l16] = p[c][r];

    bf16x8 pa[2];
#pragma unroll
    for (int kc = 0; kc < 2; kc++) {
      const float* src = pw + l16 * 68 + kc * 32 + lg * 8;
      const float4 f0 = *(const float4*)(src);
      const float4 f1 = *(const float4*)(src + 4);
      bf16x8 v;
      v[0] = (short)f2bf(f0.x); v[1] = (short)f2bf(f0.y);
      v[2] = (short)f2bf(f0.z); v[3] = (short)f2bf(f0.w);
      v[4] = (short)f2bf(f1.x); v[5] = (short)f2bf(f1.y);
      v[6] = (short)f2bf(f1.z); v[7] = (short)f2bf(f1.w);
      pa[kc] = v;
    }

#pragma unroll
    for (int nt = 0; nt < 8; nt++)
#pragma unroll
      for (int kc = 0; kc < 2; kc++) {
        const bf16x8 vf = *(const bf16x8*)(VTs + ((kc * 4 + lg) * 128 + nt * 16 + l16) * 8);
        o[nt] = __builtin_amdgcn_mfma_f32_16x16x32_bf16(pa[kc], vf, o[nt], 0, 0, 0);
      }
  }

  // epilogue -> compact row: text j, entity ntext_pad + j
  const int ntext_pad = cnt[1];
#pragma unroll
  for (int r = 0; r < 4; r++) {
    const float inv_l = 1.f / lrun[r];
    const int tok = b * S_ + qw + lg * 4 + r;
    const int j = inv[tok];
    const int crow = (ttm[tok] != 1) ? j : (ntext_pad + j);
    u16* orow = O + (size_t)crow * (H_ * D_) + h * D_ + l16;
#pragma unroll
    for (int nt = 0; nt < 8; nt++)
      orow[nt * 16] = f2bf(o[nt][r] * inv_l);
  }
}

// ------------------- mean over 4 head-replicas (entity-compact) -------------------
__global__ __launch_bounds__(256) void mean_heads_kernel(
    const u16* __restrict__ attn, u16* __restrict__ oe, const int* __restrict__ cnt)
{
  const size_t idx = (size_t)blockIdx.x * 256 + threadIdx.x;
  const int j = (int)(idx >> 10);
  if (j >= cnt[2]) return;
  const int r = (int)(idx & 1023);
  const int h = r >> 7, d = r & 127;
  const u16* a = attn + (size_t)(cnt[1] + j) * (H_ * D_);
  const float s = 0.25f * (bf2f(a[h * D_ + d]) + bf2f(a[(8 + h) * D_ + d]) +
                           bf2f(a[(16 + h) * D_ + d]) + bf2f(a[(24 + h) * D_ + d]));
  oe[idx] = f2bf(s);
}

// ------------------- scatter compact outs -> d_out with type masking -------------------
__global__ __launch_bounds__(256) void scatter_out(
    const u16* __restrict__ ct, const u16* __restrict__ ce,
    const int* __restrict__ ttm, const int* __restrict__ inv,
    float* __restrict__ out_text, float* __restrict__ out_ent)
{
  const int tok = blockIdx.x;
  const bool is_e = (ttm[tok] == 1);
  const int j = inv[tok];
  const int t = threadIdx.x;
  float* ot = out_text + (size_t)tok * HID_;
#pragma unroll
  for (int i = 0; i < 4; i++) {
    const int c = (i * 256 + t) * 4;
    float4 v = make_float4(0.f, 0.f, 0.f, 0.f);
    if (!is_e) {
      const ushort4 u = *(const ushort4*)(ct + (size_t)j * HID_ + c);
      v.x = bf2f(u.x); v.y = bf2f(u.y); v.z = bf2f(u.z); v.w = bf2f(u.w);
    }
    *(float4*)(ot + c) = v;
  }
  float* oe_ = out_ent + (size_t)tok * 1024;
  {
    const int c = t * 4;
    float4 v = make_float4(0.f, 0.f, 0.f, 0.f);
    if (is_e) {
      const ushort4 u = *(const ushort4*)(ce + (size_t)j * 1024 + c);
      v.x = bf2f(u.x); v.y = bf2f(u.y); v.z = bf2f(u.z); v.w = bf2f(u.w);
    }
    *(float4*)(oe_ + c) = v;
  }
}

// ------------------------------- launcher -------------------------------
extern "C" void kernel_launch(void* const* d_in, const int* in_sizes, int n_in,
                              void* d_out, int out_size, void* d_ws, size_t ws_size,
                              hipStream_t stream)
{
  const float* x_text = (const float*)d_in[0];
  const float* x_ent  = (const float*)d_in[1];
  const float* wq_t   = (const float*)d_in[2];
  const float* wk_t   = (const float*)d_in[3];
  const float* wv_t   = (const float*)d_in[4];
  const float* wo_t   = (const float*)d_in[5];
  const float* wq_e   = (const float*)d_in[6];
  const float* wk_e   = (const float*)d_in[7];
  const float* wv_e   = (const float*)d_in[8];
  const float* wo_e   = (const float*)d_in[9];
  const float* aq1_w = (const float*)d_in[10]; const float* aq1_b = (const float*)d_in[11];
  const float* aq2_w = (const float*)d_in[12]; const float* aq2_b = (const float*)d_in[13];
  const float* ak1_w = (const float*)d_in[14]; const float* ak1_b = (const float*)d_in[15];
  const float* ak2_w = (const float*)d_in[16]; const float* ak2_b = (const float*)d_in[17];
  const float* av1_w = (const float*)d_in[18]; const float* av1_b = (const float*)d_in[19];
  const float* av2_w = (const float*)d_in[20]; const float* av2_b = (const float*)d_in[21];
  const float* ao1_w = (const float*)d_in[22]; const float* ao1_b = (const float*)d_in[23];
  const float* ao2_w = (const float*)d_in[24]; const float* ao2_b = (const float*)d_in[25];
  const int*   ttm   = (const int*)d_in[27];
  const int*   pid   = (const int*)d_in[28];

  float* out_text = (float*)d_out;                       // [2048,4096]
  float* out_ent  = out_text + (size_t)B_ * S_ * HID_;   // [2048,1024]

  // ---- workspace layout (bytes), peak ~132.5 MB ----
  // Liveness audit (r4/r5): e_all at 25,165,824 over the qe/ke/ve span.
  // e_all live [batchA.W -> batchB.R]; qe/ke/ve live [batchC.W -> rope/vtrans.R].
  char* w = (char*)d_ws;
  u16*   qkv_bf = (u16*)(w + 0);             // 25,165,824  [2048][6144] compact text
  u16*   e_all  = (u16*)(w + 25165824);      // 12,582,912  [2048][3072] compact ent (batch A-B)
  u16*   qe     = (u16*)(w + 25165824);      //  4,194,304  [2048*8][128] (batch C+)
  u16*   ke     = (u16*)(w + 29360128);      //  4,194,304
  u16*   ve     = (u16*)(w + 33554432);      //  4,194,304
  u16*   h1q    = (u16*)(w + 37748736);      //  8,388,608  [16384][256]
  u16*   attn_bf = (u16*)(w + 0);            // 17,825,792  [2176][4096] compact
  u16*   oe_bf   = (u16*)(w + 17825792);     //  4,194,304
  u16*   h1o     = (u16*)(w + 22020096);     //  8,388,608
  u16*   oe2     = (u16*)(w + 30408704);     //  4,194,304
  u16*   xt_bf = (u16*)(w + 50331648);       // 16,777,216  [2048][4096] compact text
  u16*   Q_bf  = (u16*)(w + 50331648);       // 16,777,216  full-token
  u16*   ct_out = (u16*)(w + 50331648);      // 16,777,216  wo_t compact C
  u16*   h1k   = (u16*)(w + 62914560);       //  8,388,608  (62.9MB..71.3MB)
  u16*   xe_bf = (u16*)(w + 67108864);       //  4,194,304  [2048][1024] compact ent
  u16*   K_bf  = (u16*)(w + 67108864);       //  4,194,304  full-token
  u16*   ce_out = (u16*)(w + 67108864);      //  4,194,304  wo_e compact C
  u16*   WTb   = (u16*)(w + 71303168);       // 50,331,648  [6144][4096]
  u16*   h1v   = (u16*)(w + 71303168);       //  8,388,608  (over dead WTb, pre-WTo)
  u16*   WTo   = (u16*)(w + 71303168);       // 33,554,432  [4096][4096]
  u16*   WTao1 = (u16*)(w + 104857600);      //     65,536
  u16*   WTao2 = (u16*)(w + 104923136);      //     65,536
  u16*   WToe  = (u16*)(w + 104988672);      //  2,097,152
  u16*   WTe   = (u16*)(w + 121634816);      //  6,291,456  [3072][1024]
  u16*   WTa   = (u16*)(w + 127926272);      //    393,216  6 x [.][.]
  u16*   VT_g  = (u16*)(w + 128319488);      //  4,194,304
  int*   inv   = (int*)(w + 132513792);      //      8,192
  int*   cnt   = (int*)(w + 132521984);      //         64

  // batched GEMM launchers: segments padded to %8 blocks
  struct B128 {
    GArgs ga{}; int blk = 0;
    void add(const u16* A, const u16* Bt, const float* bias, u16* C,
             int M, int N, int K, int act, int astride, int mlimIdx) {
      GSeg& s = ga.s[ga.nseg++];
      s = {A, Bt, bias, C, N, K, act, astride, mlimIdx, blk, M >> 7, N >> 7};
      blk += ((s.nTM * s.nTN) + 7) & ~7;
    }
  };
  struct B256 {
    GArgs ga{}; int blk = 0;
    void add(const u16* A, const u16* Bt, const float* bias, u16* C,
             int M, int N, int K, int act, int astride, int mlimIdx) {
      GSeg& s = ga.s[ga.nseg++];
      s = {A, Bt, bias, C, N, K, act, astride, mlimIdx, blk, M >> 8, N >> 8};
      blk += ((s.nTM * s.nTN) + 7) & ~7;
    }
  };
  auto launch128 = [&](B128& b) {
    gemm_batch<<<dim3(b.blk), dim3(256), 0, stream>>>(b.ga, cnt);
  };
  auto launch256 = [&](B256& b) {
    gemm_batch256<<<dim3(b.blk), dim3(512), 0, stream>>>(b.ga, cnt);
  };

  // weight transposes, batch 1 (everything pre-attention)
  {
    TArgs ta{}; int blk = 0, s = 0;
    auto add = [&](const float* W, u16* Wt, int K, int N) {
      ta.s[s] = {W, Wt, K, N, blk}; blk += (K >> 5) * (N >> 5); s++;
    };
    add(wq_t, WTb, HID_, HID_);
    add(wk_t, WTb + (size_t)4096 * HID_, HID_, 1024);
    add(wv_t, WTb + (size_t)5120 * HID_, HID_, 1024);
    add(wq_e, WTe, 1024, 1024);
    add(wk_e, WTe + (size_t)1024 * 1024, 1024, 1024);
    add(wv_e, WTe + (size_t)2048 * 1024, 1024, 1024);
    add(aq1_w, WTa,          D_, AH_);
    add(aq2_w, WTa + 32768,  AH_, D_);
    add(ak1_w, WTa + 65536,  D_, AH_);
    add(ak2_w, WTa + 98304,  AH_, D_);
    add(av1_w, WTa + 131072, D_, AH_);
    add(av2_w, WTa + 163840, AH_, D_);
    ta.nseg = s;
    batch_transpose<<<dim3(blk), dim3(256), 0, stream>>>(ta);
  }

  // token-type scan + input gather
  build_inv<<<dim3(1), dim3(1024), 0, stream>>>(ttm, inv, cnt);
  gather_cast<<<dim3(NTOK), dim3(256), 0, stream>>>(x_text, x_ent, ttm, inv, xt_bf, xe_bf);

  // batch A (256^2): text QKV || entity projection (disjoint regions)
  //   seg0 R:{xt_bf,WTb} W:{qkv_bf}   seg1 R:{xe_bf,WTe} W:{e_all@25.2MB}
  {
    B256 b;
    b.add(xt_bf, WTb, nullptr, qkv_bf, NTOK, 6144, HID_, 0, 0, 1);
    b.add(xe_bf, WTe, nullptr, e_all, NTOK, 3072, 1024, 0, 0, 3);
    launch256(b);
  }
  // batch B (128^2): adapter layer-1 q||k||v (share input e_all; outputs disjoint)
  {
    B128 b;
    b.add(e_all,        WTa,          aq1_b, h1q, NTOK * 8, AH_, D_, 1, 3072, 4);
    b.add(e_all + 1024, WTa + 65536,  ak1_b, h1k, NTOK * 8, AH_, D_, 1, 3072, 4);
    b.add(e_all + 2048, WTa + 131072, av1_b, h1v, NTOK * 8, AH_, D_, 1, 3072, 4);
    launch128(b);
  }
  // batch C (128^2): adapter layer-2 q||k||v (write qe/ke/ve over dead e_all)
  {
    B128 b;
    b.add(h1q, WTa + 32768,  aq2_b, qe, NTOK * 8, D_, AH_, 0, 0, 4);
    b.add(h1k, WTa + 98304,  ak2_b, ke, NTOK * 8, D_, AH_, 0, 0, 4);
    b.add(h1v, WTa + 163840, av2_b, ve, NTOK * 8, D_, AH_, 0, 0, 4);
    launch128(b);
  }

  // select + RoPE -> full-token Q/K bf16; V transpose
  select_rope_bf<<<dim3(NTOK), dim3(256), 0, stream>>>(
      qkv_bf, qe, ke, Q_bf, K_bf, ttm, inv, pid);
  vtrans_kernel<<<dim3(B_ * KVH_ * 32 * 4), dim3(256), 0, stream>>>(
      qkv_bf, ve, ttm, inv, VT_g);

  // weight transposes, batch 2 (into dead WTb region; h1v already consumed)
  {
    TArgs ta{}; int blk = 0, s = 0;
    auto add = [&](const float* W, u16* Wt, int K, int N) {
      ta.s[s] = {W, Wt, K, N, blk}; blk += (K >> 5) * (N >> 5); s++;
    };
    add(wo_t, WTo, HID_, HID_);
    add(ao1_w, WTao1, D_, AH_);
    add(ao2_w, WTao2, AH_, D_);
    add(wo_e, WToe, 1024, 1024);
    ta.nseg = s;
    batch_transpose<<<dim3(blk), dim3(256), 0, stream>>>(ta);
  }

  // MFMA flash attention -> compact bf16 (text rows [0,ntext), entity at ntext_pad)
  attn_mfma<<<dim3(B_ * H_ * 16), dim3(256), 0, stream>>>(
      Q_bf, K_bf, VT_g, attn_bf, ttm, inv, cnt);

  // entity mean, then adapter-out layer-1 (128^2), then wo_t (256^2)
  mean_heads_kernel<<<dim3(NTOK * 1024 / 256), dim3(256), 0, stream>>>(attn_bf, oe_bf, cnt);
  {
    B128 b; b.add(oe_bf, WTao1, ao1_b, h1o, NTOK * 8, AH_, D_, 1, 0, 4); launch128(b);
  }
  {
    B256 b; b.add(attn_bf, WTo, nullptr, ct_out, NTOK, HID_, HID_, 0, 0, 1); launch256(b);
  }
  // serial tail of entity chain (128^2)
  {
    B128 b; b.add(h1o, WTao2, ao2_b, oe2, NTOK * 8, D_, AH_, 0, 0, 4); launch128(b);
  }
  {
    B128 b; b.add(oe2, WToe, nullptr, ce_out, NTOK, 1024, 1024, 0, 0, 3); launch128(b);
  }

  // scatter to d_out with token-type masking
  scatter_out<<<dim3(NTOK), dim3(256), 0, stream>>>(
      ct_out, ce_out, ttm, inv, out_text, out_ent);
}

// Round 7
// 682.056 us; speedup vs baseline: 1.5166x; 1.5166x over previous
//
#include <hip/hip_runtime.h>
#include <cstdint>
#include <cstddef>

// Problem constants (reference: B=2,S=1024,HID=4096,H=32,D=128,KVH=8,EH=8,AH=256)
#define B_    2
#define S_    1024
#define HID_  4096
#define H_    32
#define D_    128
#define KVH_  8
#define EH_   8
#define AH_   256
#define NTOK  2048

typedef unsigned short u16;
typedef __attribute__((ext_vector_type(8))) short bf16x8;
typedef __attribute__((ext_vector_type(4))) float f32x4;
typedef const __attribute__((address_space(1))) void* gp_t;
typedef __attribute__((address_space(3))) void* lp_t;

__device__ __forceinline__ u16 f2bf(float f) {              // RNE f32->bf16
  unsigned u = __float_as_uint(f);
  return (u16)((u + 0x7FFF + ((u >> 16) & 1)) >> 16);
}
__device__ __forceinline__ float bf2f(u16 u) {
  return __uint_as_float((unsigned)u << 16);
}

// --------------- token-type scan: inv[] + counts (1 block) ---------------
// inv[t] = compact index within its type. cnt = {ntext, ntext_pad, nent,
// nent_pad, ceil128(nent*8), _}
__global__ __launch_bounds__(1024) void build_inv(
    const int* __restrict__ ttm, int* __restrict__ inv, int* __restrict__ cnt)
{
  __shared__ int a[NTOK], b[NTOK];
  const int t = threadIdx.x;
  for (int i = t; i < NTOK; i += 1024) a[i] = (ttm[i] != 1) ? 1 : 0;
  __syncthreads();
  int* src = a; int* dst = b;
  for (int off = 1; off < NTOK; off <<= 1) {
    for (int i = t; i < NTOK; i += 1024)
      dst[i] = src[i] + ((i >= off) ? src[i - off] : 0);
    __syncthreads();
    int* tmp = src; src = dst; dst = tmp;
  }
  for (int i = t; i < NTOK; i += 1024) {
    const int txt = (ttm[i] != 1);
    const int excl = src[i] - txt;
    inv[i] = txt ? excl : (i - excl);
  }
  if (t == 0) {
    const int ntext = src[NTOK - 1];
    const int nent = NTOK - ntext;
    cnt[0] = ntext;
    cnt[1] = (ntext + 127) & ~127;
    cnt[2] = nent;
    cnt[3] = (nent + 127) & ~127;
    cnt[4] = (nent * 8 + 127) & ~127;
  }
}

// --------------- gather inputs to per-type compact bf16 ---------------
__global__ __launch_bounds__(256) void gather_cast(
    const float* __restrict__ x_text, const float* __restrict__ x_ent,
    const int* __restrict__ ttm, const int* __restrict__ inv,
    u16* __restrict__ xt, u16* __restrict__ xe)
{
  const int tok = blockIdx.x;
  const int j = inv[tok];
  const int t = threadIdx.x;
  if (ttm[tok] != 1) {
    const float* src = x_text + (size_t)tok * HID_;
    u16* dst = xt + (size_t)j * HID_;
#pragma unroll
    for (int i = 0; i < 4; i++) {
      const int c = (i * 256 + t) * 4;
      const float4 v = *(const float4*)(src + c);
      ushort4 o; o.x = f2bf(v.x); o.y = f2bf(v.y); o.z = f2bf(v.z); o.w = f2bf(v.w);
      *(ushort4*)(dst + c) = o;
    }
  } else {
    const float* src = x_ent + (size_t)tok * 1024;
    u16* dst = xe + (size_t)j * 1024;
    const int c = t * 4;
    const float4 v = *(const float4*)(src + c);
    ushort4 o; o.x = f2bf(v.x); o.y = f2bf(v.y); o.z = f2bf(v.z); o.w = f2bf(v.w);
    *(ushort4*)(dst + c) = o;
  }
}

// ---------------- batched weight transpose+cast ----------------
struct TSeg { const float* W; u16* Wt; int K; int N; int blk0; };
struct TArgs { TSeg s[12]; int nseg; };

__global__ __launch_bounds__(256) void batch_transpose(TArgs args)
{
  int seg = 0;
#pragma unroll
  for (int i = 1; i < 12; i++)
    if (i < args.nseg && (int)blockIdx.x >= args.s[i].blk0) seg = i;
  const float* W = args.s[seg].W;
  u16* Wt = args.s[seg].Wt;
  const int K = args.s[seg].K, N = args.s[seg].N;
  const int local = blockIdx.x - args.s[seg].blk0;

  __shared__ float tle[32][33];
  const int tid = threadIdx.x;
  const int tx = tid & 31, ty = tid >> 5;
  const int nb = N >> 5;
  const int k0 = (local / nb) << 5;
  const int n0 = (local % nb) << 5;
#pragma unroll
  for (int r = 0; r < 32; r += 8)
    tle[ty + r][tx] = W[(size_t)(k0 + ty + r) * N + n0 + tx];
  __syncthreads();
#pragma unroll
  for (int r = 0; r < 32; r += 8)
    Wt[(size_t)(n0 + ty + r) * K + k0 + tx] = f2bf(tle[tx][ty + r]);
}

// --------------------- batched bf16 MFMA GEMM, 128x128 tile ---------------------
// m97 2-barrier K-loop. Segments concurrent: no output/input aliasing within
// one dispatch (r4 lesson).
//
// COALESCED STAGING (r6 diagnosis): previous lane->row mapping made every
// global_load_lds a 64-distinct-cache-line gather (16B used/line, stride 8KB)
// -> ~1024 line-transactions per K-step per block -> per-CU L1/TA transaction
// rate was the true bottleneck (invariant to scheduling/occupancy/tile-size,
// which is why r1-r6's levers were all null). New mapping: linear chunk index
// L = tid + inst*256, row = L>>2, chunk = L&3 -> 4 consecutive lanes read the
// four 16B chunks of ONE 64B row-line: 16 lines/instr (4x fewer). LDS becomes
// row-major [128 rows][64 B] (global_load_lds writes base+lane*16 in L order);
// fragment reads use offset row*64 + lg*16.
struct GSeg {
  const u16* A; const u16* Bt; const float* bias; u16* C;
  int N, K, act, astride, mlimIdx, blk0, nTM, nTN;
};
struct GArgs { GSeg s[4]; int nseg; };

__global__ __launch_bounds__(256) void gemm_batch(GArgs ga, const int* __restrict__ cnt)
{
  int seg = 0;
#pragma unroll
  for (int i = 1; i < 4; i++)
    if (i < ga.nseg && (int)blockIdx.x >= ga.s[i].blk0) seg = i;
  const GSeg sg = ga.s[seg];
  const int local = (int)blockIdx.x - sg.blk0;
  const int nTM = sg.nTM, nTN = sg.nTN;
  const int nwg = nTM * nTN;
  if (local >= nwg) return;                       // segment padding

  // bijective XCD swizzle (m204) + column-major tile order + row-stride perm
  const int xcd = local & 7, lix = local >> 3;
  const int q = nwg >> 3, rr_ = nwg & 7;
  const int wgid = (xcd < rr_ ? xcd * (q + 1) : rr_ * (q + 1) + (xcd - rr_) * q) + lix;
  const int tcol = wgid / nTM;
  int trow = wgid - tcol * nTM;
  if ((nTM & 7) == 0) trow = ((trow & 7) * (nTM >> 3)) + (trow >> 3);
  const int m0 = trow << 7;
  if (sg.mlimIdx >= 0 && m0 >= cnt[sg.mlimIdx]) return;
  const int n0 = tcol << 7;

  const int N = sg.N, K = sg.K;
  const u16* __restrict__ A = sg.A;
  const u16* __restrict__ Bt = sg.Bt;

  __shared__ __align__(16) char AsB[8192];   // [row 128][64 B] row-major
  __shared__ __align__(16) char BsB[8192];

  const int tid = threadIdx.x;
  const int wave = tid >> 6, lane = tid & 63;
  const int wm = ((wave >> 1) << 6);
  const int wn = ((wave & 1) << 6);
  const int l16 = lane & 15, lg = lane >> 4;

  // coalesced staging map: L = tid + inst*256; row = L>>2, chunk = L&3
  const int L0 = tid, L1 = tid + 256;
  const int r0 = L0 >> 2, g0 = L0 & 3;
  const int r1 = L1 >> 2, g1 = L1 & 3;

  auto arow = [&](int row) -> size_t {
    return sg.astride ? (size_t)(row >> 3) * sg.astride + (size_t)(row & 7) * K
                      : (size_t)row * K;
  };
  const u16* a0 = A + arow(m0 + r0) + g0 * 8;
  const u16* a1 = A + arow(m0 + r1) + g1 * 8;
  const u16* b0 = Bt + (size_t)(n0 + r0) * K + g0 * 8;
  const u16* b1 = Bt + (size_t)(n0 + r1) * K + g1 * 8;

  // LDS dest bases (HW adds lane*16): offset(L) = L*16 = wave*1024 + lane*16 (+ inst*4096)
  const int dst0 = wave * 1024;
  const int dst1 = wave * 1024 + 4096;

  f32x4 acc[4][4];
#pragma unroll
  for (int i = 0; i < 4; i++)
#pragma unroll
    for (int j = 0; j < 4; j++) acc[i][j] = (f32x4)0.f;

  for (int k0 = 0; k0 < K; k0 += 32) {
    if (k0) __syncthreads();
    __builtin_amdgcn_global_load_lds((gp_t)a0, (lp_t)(AsB + dst0), 16, 0, 0);
    __builtin_amdgcn_global_load_lds((gp_t)a1, (lp_t)(AsB + dst1), 16, 0, 0);
    __builtin_amdgcn_global_load_lds((gp_t)b0, (lp_t)(BsB + dst0), 16, 0, 0);
    __builtin_amdgcn_global_load_lds((gp_t)b1, (lp_t)(BsB + dst1), 16, 0, 0);
    a0 += 32; a1 += 32; b0 += 32; b1 += 32;
    __syncthreads();

    bf16x8 af[4], bv[4];
#pragma unroll
    for (int i = 0; i < 4; i++)
      af[i] = *(const bf16x8*)(AsB + (wm + 16 * i + l16) * 64 + lg * 16);
#pragma unroll
    for (int j = 0; j < 4; j++)
      bv[j] = *(const bf16x8*)(BsB + (wn + 16 * j + l16) * 64 + lg * 16);
#pragma unroll
    for (int i = 0; i < 4; i++)
#pragma unroll
      for (int j = 0; j < 4; j++)
        acc[i][j] = __builtin_amdgcn_mfma_f32_16x16x32_bf16(af[i], bv[j], acc[i][j], 0, 0, 0);
  }

  // epilogue: C/D map col=lane&15, row=(lane>>4)*4+reg
#pragma unroll
  for (int i = 0; i < 4; i++) {
#pragma unroll
    for (int r = 0; r < 4; r++) {
      const int row = m0 + wm + 16 * i + lg * 4 + r;
#pragma unroll
      for (int j = 0; j < 4; j++) {
        const int col = n0 + wn + 16 * j + l16;
        float c = acc[i][j][r];
        if (sg.bias) c += sg.bias[col];
        if (sg.act) c = 0.5f * c * (1.f + erff(c * 0.70710678118654752f));  // exact GELU
        sg.C[(size_t)row * N + col] = f2bf(c);
      }
    }
  }
}

// ------------- select + RoPE -> bf16 Q (prescaled), bf16 K (full token index) -------------
__global__ __launch_bounds__(256) void select_rope_bf(
    const u16* __restrict__ qkv, const u16* __restrict__ qe,
    const u16* __restrict__ ke, u16* __restrict__ Qb, u16* __restrict__ Kb,
    const int* __restrict__ ttm, const int* __restrict__ inv,
    const int* __restrict__ pid)
{
  __shared__ float cs[64], sn[64];
  const int token = blockIdx.x;
  const bool is_e = (ttm[token] == 1);
  const int j = inv[token];
  const int t = threadIdx.x;
  if (t < 64) {
    const float pos = (float)pid[token];
    const float iv = __expf(-((float)(2 * t) * (1.f / 128.f)) * 9.210340371976184f);
    const float f = pos * iv;
    cs[t] = cosf(f); sn[t] = sinf(f);
  }
  __syncthreads();
  const float scale = 0.08838834764831845f;  // 1/sqrt(128) folded into Q
  const u16* qrow = qkv + (size_t)j * 6144;

  for (int it = t; it < H_ * 64; it += 256) {
    const int h = it >> 6, i = it & 63;
    float x1, x2;
    if (is_e) {
      const size_t eb = ((size_t)j * 8 + (h & 7)) * D_;
      x1 = bf2f(qe[eb + i]); x2 = bf2f(qe[eb + i + 64]);
    } else {
      x1 = bf2f(qrow[h * 128 + i]); x2 = bf2f(qrow[h * 128 + i + 64]);
    }
    const size_t base = ((size_t)token * H_ + h) * D_;
    Qb[base + i]      = f2bf((x1 * cs[i] - x2 * sn[i]) * scale);
    Qb[base + i + 64] = f2bf((x2 * cs[i] + x1 * sn[i]) * scale);
  }
  for (int it = t; it < KVH_ * 64; it += 256) {
    const int h = it >> 6, i = it & 63;
    float x1, x2;
    if (is_e) {
      const size_t eb = ((size_t)j * 8 + h) * D_;
      x1 = bf2f(ke[eb + i]); x2 = bf2f(ke[eb + i + 64]);
    } else {
      x1 = bf2f(qrow[4096 + h * 128 + i]); x2 = bf2f(qrow[4096 + h * 128 + i + 64]);
    }
    const size_t base = ((size_t)token * KVH_ + h) * D_;
    Kb[base + i]      = f2bf(x1 * cs[i] - x2 * sn[i]);
    Kb[base + i + 64] = f2bf(x2 * cs[i] + x1 * sn[i]);
  }
}

// ---------- V select + transpose: VT[b][hk][d][s] bf16 ----------
__global__ __launch_bounds__(256) void vtrans_kernel(
    const u16* __restrict__ qkv, const u16* __restrict__ ve,
    const int* __restrict__ ttm, const int* __restrict__ inv,
    u16* __restrict__ VTg)
{
  __shared__ float t[32][33];
  const int dt = blockIdx.x & 3;
  const int st = (blockIdx.x >> 2) & 31;
  const int hk = (blockIdx.x >> 7) & 7;
  const int b  = blockIdx.x >> 10;
  const int s0 = st * 32, d0 = dt * 32;
  const int tx = threadIdx.x & 31, ty = threadIdx.x >> 5;
#pragma unroll
  for (int i = 0; i < 4; i++) {
    const int r = ty + 8 * i;
    const int tok = b * S_ + s0 + r;
    const int j = inv[tok];
    t[r][tx] = (ttm[tok] == 1)
        ? bf2f(ve[((size_t)j * 8 + hk) * D_ + d0 + tx])
        : bf2f(qkv[(size_t)j * 6144 + 5120 + hk * 128 + d0 + tx]);
  }
  __syncthreads();
#pragma unroll
  for (int i = 0; i < 4; i++) {
    const int rr = ty + 8 * i;
    VTg[((size_t)(b * KVH_ + hk) * D_ + d0 + rr) * S_ + s0 + tx] = f2bf(t[tx][rr]);
  }
}

// ------------------- MFMA causal GQA flash attention (compact output) -------------------
__global__ __launch_bounds__(256) void attn_mfma(
    const u16* __restrict__ Qb, const u16* __restrict__ Kb,
    const u16* __restrict__ VTg, u16* __restrict__ O,
    const int* __restrict__ ttm, const int* __restrict__ inv,
    const int* __restrict__ cnt)
{
  __shared__ __align__(16) u16 Ks[16 * 64 * 8];
  __shared__ __align__(16) u16 VTs[8 * 128 * 8];
  __shared__ __align__(16) float Ps[4][16 * 68];

  const int tid = threadIdx.x;
  const int wave = tid >> 6, lane = tid & 63;
  const int l16 = lane & 15, lg = lane >> 4;

  const int qtile = 15 - (blockIdx.x & 15);
  const int h = (blockIdx.x >> 4) & (H_ - 1);
  const int b = blockIdx.x >> 9;
  const int q0 = qtile * 64;
  const int hk = h & 7;
  const int qw = q0 + 16 * wave;
  const int qmax = qw + 15;

  bf16x8 qf[4];
  {
    const u16* qrow = Qb + ((size_t)(b * S_ + qw + l16) * H_ + h) * D_;
#pragma unroll
    for (int c = 0; c < 4; c++)
      qf[c] = *(const bf16x8*)(qrow + c * 32 + lg * 8);
  }

  f32x4 o[8];
#pragma unroll
  for (int nt = 0; nt < 8; nt++) o[nt] = (f32x4)0.f;
  float mrun[4] = {-1e30f, -1e30f, -1e30f, -1e30f};
  float lrun[4] = {0.f, 0.f, 0.f, 0.f};

  const int ntiles = qtile + 1;
  for (int t = 0; t < ntiles; t++) {
    const int k0 = t * 64;
    if (t) __syncthreads();
#pragma unroll
    for (int i = 0; i < 4; i++) {
      const int idx = i * 256 + tid;
      const int g = idx >> 6, key = idx & 63;
      *(bf16x8*)(Ks + idx * 8) =
          *(const bf16x8*)(Kb + ((size_t)(b * S_ + k0 + key) * KVH_ + hk) * D_ + g * 8);
    }
#pragma unroll
    for (int i = 0; i < 4; i++) {
      const int idx = i * 256 + tid;
      const int kg = idx >> 7, d = idx & 127;
      *(bf16x8*)(VTs + idx * 8) =
          *(const bf16x8*)(VTg + ((size_t)(b * KVH_ + hk) * D_ + d) * S_ + k0 + kg * 8);
    }
    __syncthreads();

    if (k0 > qmax) continue;

    f32x4 s[4];
#pragma unroll
    for (int c = 0; c < 4; c++) s[c] = (f32x4)0.f;
#pragma unroll
    for (int c = 0; c < 4; c++)
#pragma unroll
      for (int dc = 0; dc < 4; dc++) {
        const bf16x8 kf = *(const bf16x8*)(Ks + ((dc * 4 + lg) * 64 + c * 16 + l16) * 8);
        s[c] = __builtin_amdgcn_mfma_f32_16x16x32_bf16(qf[dc], kf, s[c], 0, 0, 0);
      }

    float p[4][4], alpha[4];
#pragma unroll
    for (int r = 0; r < 4; r++) {
      const int qg = qw + lg * 4 + r;
      float sv[4], mx = -1e30f;
#pragma unroll
      for (int c = 0; c < 4; c++) {
        const int kg_ = k0 + c * 16 + l16;
        float v = (kg_ <= qg) ? s[c][r] : -1e30f;
        sv[c] = v;
        mx = fmaxf(mx, v);
      }
#pragma unroll
      for (int off = 1; off < 16; off <<= 1)
        mx = fmaxf(mx, __shfl_xor(mx, off));
      const float mn = fmaxf(mrun[r], mx);
      alpha[r] = __expf(mrun[r] - mn);
      mrun[r] = mn;
      float rs = 0.f;
#pragma unroll
      for (int c = 0; c < 4; c++) { p[c][r] = __expf(sv[c] - mn); rs += p[c][r]; }
#pragma unroll
      for (int off = 1; off < 16; off <<= 1)
        rs += __shfl_xor(rs, off);
      lrun[r] = lrun[r] * alpha[r] + rs;
    }
#pragma unroll
    for (int nt = 0; nt < 8; nt++)
#pragma unroll
      for (int r = 0; r < 4; r++) o[nt][r] *= alpha[r];

    float* pw = Ps[wave];
#pragma unroll
    for (int c = 0; c < 4; c++)
#pragma unroll
      for (int r = 0; r < 4; r++)
        pw[(lg * 4 + r) * 68 + c * 16 + l16] = p[c][r];

    bf16x8 pa[2];
#pragma unroll
    for (int kc = 0; kc < 2; kc++) {
      const float* src = pw + l16 * 68 + kc * 32 + lg * 8;
      const float4 f0 = *(const float4*)(src);
      const float4 f1 = *(const float4*)(src + 4);
      bf16x8 v;
      v[0] = (short)f2bf(f0.x); v[1] = (short)f2bf(f0.y);
      v[2] = (short)f2bf(f0.z); v[3] = (short)f2bf(f0.w);
      v[4] = (short)f2bf(f1.x); v[5] = (short)f2bf(f1.y);
      v[6] = (short)f2bf(f1.z); v[7] = (short)f2bf(f1.w);
      pa[kc] = v;
    }

#pragma unroll
    for (int nt = 0; nt < 8; nt++)
#pragma unroll
      for (int kc = 0; kc < 2; kc++) {
        const bf16x8 vf = *(const bf16x8*)(VTs + ((kc * 4 + lg) * 128 + nt * 16 + l16) * 8);
        o[nt] = __builtin_amdgcn_mfma_f32_16x16x32_bf16(pa[kc], vf, o[nt], 0, 0, 0);
      }
  }

  // epilogue -> compact row: text j, entity ntext_pad + j
  const int ntext_pad = cnt[1];
#pragma unroll
  for (int r = 0; r < 4; r++) {
    const float inv_l = 1.f / lrun[r];
    const int tok = b * S_ + qw + lg * 4 + r;
    const int j = inv[tok];
    const int crow = (ttm[tok] != 1) ? j : (ntext_pad + j);
    u16* orow = O + (size_t)crow * (H_ * D_) + h * D_ + l16;
#pragma unroll
    for (int nt = 0; nt < 8; nt++)
      orow[nt * 16] = f2bf(o[nt][r] * inv_l);
  }
}

// ------------------- mean over 4 head-replicas (entity-compact) -------------------
__global__ __launch_bounds__(256) void mean_heads_kernel(
    const u16* __restrict__ attn, u16* __restrict__ oe, const int* __restrict__ cnt)
{
  const size_t idx = (size_t)blockIdx.x * 256 + threadIdx.x;
  const int j = (int)(idx >> 10);
  if (j >= cnt[2]) return;
  const int r = (int)(idx & 1023);
  const int h = r >> 7, d = r & 127;
  const u16* a = attn + (size_t)(cnt[1] + j) * (H_ * D_);
  const float s = 0.25f * (bf2f(a[h * D_ + d]) + bf2f(a[(8 + h) * D_ + d]) +
                           bf2f(a[(16 + h) * D_ + d]) + bf2f(a[(24 + h) * D_ + d]));
  oe[idx] = f2bf(s);
}

// ------------------- scatter compact outs -> d_out with type masking -------------------
__global__ __launch_bounds__(256) void scatter_out(
    const u16* __restrict__ ct, const u16* __restrict__ ce,
    const int* __restrict__ ttm, const int* __restrict__ inv,
    float* __restrict__ out_text, float* __restrict__ out_ent)
{
  const int tok = blockIdx.x;
  const bool is_e = (ttm[tok] == 1);
  const int j = inv[tok];
  const int t = threadIdx.x;
  float* ot = out_text + (size_t)tok * HID_;
#pragma unroll
  for (int i = 0; i < 4; i++) {
    const int c = (i * 256 + t) * 4;
    float4 v = make_float4(0.f, 0.f, 0.f, 0.f);
    if (!is_e) {
      const ushort4 u = *(const ushort4*)(ct + (size_t)j * HID_ + c);
      v.x = bf2f(u.x); v.y = bf2f(u.y); v.z = bf2f(u.z); v.w = bf2f(u.w);
    }
    *(float4*)(ot + c) = v;
  }
  float* oe_ = out_ent + (size_t)tok * 1024;
  {
    const int c = t * 4;
    float4 v = make_float4(0.f, 0.f, 0.f, 0.f);
    if (is_e) {
      const ushort4 u = *(const ushort4*)(ce + (size_t)j * 1024 + c);
      v.x = bf2f(u.x); v.y = bf2f(u.y); v.z = bf2f(u.z); v.w = bf2f(u.w);
    }
    *(float4*)(oe_ + c) = v;
  }
}

// ------------------------------- launcher -------------------------------
extern "C" void kernel_launch(void* const* d_in, const int* in_sizes, int n_in,
                              void* d_out, int out_size, void* d_ws, size_t ws_size,
                              hipStream_t stream)
{
  const float* x_text = (const float*)d_in[0];
  const float* x_ent  = (const float*)d_in[1];
  const float* wq_t   = (const float*)d_in[2];
  const float* wk_t   = (const float*)d_in[3];
  const float* wv_t   = (const float*)d_in[4];
  const float* wo_t   = (const float*)d_in[5];
  const float* wq_e   = (const float*)d_in[6];
  const float* wk_e   = (const float*)d_in[7];
  const float* wv_e   = (const float*)d_in[8];
  const float* wo_e   = (const float*)d_in[9];
  const float* aq1_w = (const float*)d_in[10]; const float* aq1_b = (const float*)d_in[11];
  const float* aq2_w = (const float*)d_in[12]; const float* aq2_b = (const float*)d_in[13];
  const float* ak1_w = (const float*)d_in[14]; const float* ak1_b = (const float*)d_in[15];
  const float* ak2_w = (const float*)d_in[16]; const float* ak2_b = (const float*)d_in[17];
  const float* av1_w = (const float*)d_in[18]; const float* av1_b = (const float*)d_in[19];
  const float* av2_w = (const float*)d_in[20]; const float* av2_b = (const float*)d_in[21];
  const float* ao1_w = (const float*)d_in[22]; const float* ao1_b = (const float*)d_in[23];
  const float* ao2_w = (const float*)d_in[24]; const float* ao2_b = (const float*)d_in[25];
  const int*   ttm   = (const int*)d_in[27];
  const int*   pid   = (const int*)d_in[28];

  float* out_text = (float*)d_out;                       // [2048,4096]
  float* out_ent  = out_text + (size_t)B_ * S_ * HID_;   // [2048,1024]

  // ---- workspace layout (bytes), peak ~132.5 MB ----
  // Liveness audit (r4/r5): e_all at 25,165,824 over the qe/ke/ve span.
  // e_all live [batchA.W -> batchB.R]; qe/ke/ve live [batchC.W -> rope/vtrans.R].
  char* w = (char*)d_ws;
  u16*   qkv_bf = (u16*)(w + 0);             // 25,165,824  [2048][6144] compact text
  u16*   e_all  = (u16*)(w + 25165824);      // 12,582,912  [2048][3072] compact ent (batch A-B)
  u16*   qe     = (u16*)(w + 25165824);      //  4,194,304  [2048*8][128] (batch C+)
  u16*   ke     = (u16*)(w + 29360128);      //  4,194,304
  u16*   ve     = (u16*)(w + 33554432);      //  4,194,304
  u16*   h1q    = (u16*)(w + 37748736);      //  8,388,608  [16384][256]
  u16*   attn_bf = (u16*)(w + 0);            // 17,825,792  [2176][4096] compact
  u16*   oe_bf   = (u16*)(w + 17825792);     //  4,194,304
  u16*   h1o     = (u16*)(w + 22020096);     //  8,388,608
  u16*   oe2     = (u16*)(w + 30408704);     //  4,194,304
  u16*   xt_bf = (u16*)(w + 50331648);       // 16,777,216  [2048][4096] compact text
  u16*   Q_bf  = (u16*)(w + 50331648);       // 16,777,216  full-token
  u16*   ct_out = (u16*)(w + 50331648);      // 16,777,216  wo_t compact C
  u16*   h1k   = (u16*)(w + 62914560);       //  8,388,608  (62.9MB..71.3MB)
  u16*   xe_bf = (u16*)(w + 67108864);       //  4,194,304  [2048][1024] compact ent
  u16*   K_bf  = (u16*)(w + 67108864);       //  4,194,304  full-token
  u16*   ce_out = (u16*)(w + 67108864);      //  4,194,304  wo_e compact C
  u16*   WTb   = (u16*)(w + 71303168);       // 50,331,648  [6144][4096]
  u16*   h1v   = (u16*)(w + 71303168);       //  8,388,608  (over dead WTb, pre-WTo)
  u16*   WTo   = (u16*)(w + 71303168);       // 33,554,432  [4096][4096]
  u16*   WTao1 = (u16*)(w + 104857600);      //     65,536
  u16*   WTao2 = (u16*)(w + 104923136);      //     65,536
  u16*   WToe  = (u16*)(w + 104988672);      //  2,097,152
  u16*   WTe   = (u16*)(w + 121634816);      //  6,291,456  [3072][1024]
  u16*   WTa   = (u16*)(w + 127926272);      //    393,216  6 x [.][.]
  u16*   VT_g  = (u16*)(w + 128319488);      //  4,194,304
  int*   inv   = (int*)(w + 132513792);      //      8,192
  int*   cnt   = (int*)(w + 132521984);      //         64

  // batched GEMM launcher: segments padded to %8 blocks
  struct B {
    GArgs ga{}; int blk = 0;
    void add(const u16* A, const u16* Bt, const float* bias, u16* C,
             int M, int N, int K, int act, int astride, int mlimIdx) {
      GSeg& s = ga.s[ga.nseg++];
      s = {A, Bt, bias, C, N, K, act, astride, mlimIdx, blk, M >> 7, N >> 7};
      blk += ((s.nTM * s.nTN) + 7) & ~7;
    }
  };
  auto launch = [&](B& b) {
    gemm_batch<<<dim3(b.blk), dim3(256), 0, stream>>>(b.ga, cnt);
  };

  // weight transposes, batch 1 (everything pre-attention)
  {
    TArgs ta{}; int blk = 0, s = 0;
    auto add = [&](const float* W, u16* Wt, int K, int N) {
      ta.s[s] = {W, Wt, K, N, blk}; blk += (K >> 5) * (N >> 5); s++;
    };
    add(wq_t, WTb, HID_, HID_);
    add(wk_t, WTb + (size_t)4096 * HID_, HID_, 1024);
    add(wv_t, WTb + (size_t)5120 * HID_, HID_, 1024);
    add(wq_e, WTe, 1024, 1024);
    add(wk_e, WTe + (size_t)1024 * 1024, 1024, 1024);
    add(wv_e, WTe + (size_t)2048 * 1024, 1024, 1024);
    add(aq1_w, WTa,          D_, AH_);
    add(aq2_w, WTa + 32768,  AH_, D_);
    add(ak1_w, WTa + 65536,  D_, AH_);
    add(ak2_w, WTa + 98304,  AH_, D_);
    add(av1_w, WTa + 131072, D_, AH_);
    add(av2_w, WTa + 163840, AH_, D_);
    ta.nseg = s;
    batch_transpose<<<dim3(blk), dim3(256), 0, stream>>>(ta);
  }

  // token-type scan + input gather
  build_inv<<<dim3(1), dim3(1024), 0, stream>>>(ttm, inv, cnt);
  gather_cast<<<dim3(NTOK), dim3(256), 0, stream>>>(x_text, x_ent, ttm, inv, xt_bf, xe_bf);

  // batch A: text QKV || entity projection (disjoint regions)
  //   seg0 R:{xt_bf,WTb} W:{qkv_bf}   seg1 R:{xe_bf,WTe} W:{e_all@25.2MB}
  {
    B b;
    b.add(xt_bf, WTb, nullptr, qkv_bf, NTOK, 6144, HID_, 0, 0, 1);
    b.add(xe_bf, WTe, nullptr, e_all, NTOK, 3072, 1024, 0, 0, 3);
    launch(b);
  }
  // batch B: adapter layer-1 q||k||v (share input e_all; outputs disjoint)
  {
    B b;
    b.add(e_all,        WTa,          aq1_b, h1q, NTOK * 8, AH_, D_, 1, 3072, 4);
    b.add(e_all + 1024, WTa + 65536,  ak1_b, h1k, NTOK * 8, AH_, D_, 1, 3072, 4);
    b.add(e_all + 2048, WTa + 131072, av1_b, h1v, NTOK * 8, AH_, D_, 1, 3072, 4);
    launch(b);
  }
  // batch C: adapter layer-2 q||k||v (write qe/ke/ve over dead e_all)
  {
    B b;
    b.add(h1q, WTa + 32768,  aq2_b, qe, NTOK * 8, D_, AH_, 0, 0, 4);
    b.add(h1k, WTa + 98304,  ak2_b, ke, NTOK * 8, D_, AH_, 0, 0, 4);
    b.add(h1v, WTa + 163840, av2_b, ve, NTOK * 8, D_, AH_, 0, 0, 4);
    launch(b);
  }

  // select + RoPE -> full-token Q/K bf16; V transpose
  select_rope_bf<<<dim3(NTOK), dim3(256), 0, stream>>>(
      qkv_bf, qe, ke, Q_bf, K_bf, ttm, inv, pid);
  vtrans_kernel<<<dim3(B_ * KVH_ * 32 * 4), dim3(256), 0, stream>>>(
      qkv_bf, ve, ttm, inv, VT_g);

  // weight transposes, batch 2 (into dead WTb region; h1v already consumed)
  {
    TArgs ta{}; int blk = 0, s = 0;
    auto add = [&](const float* W, u16* Wt, int K, int N) {
      ta.s[s] = {W, Wt, K, N, blk}; blk += (K >> 5) * (N >> 5); s++;
    };
    add(wo_t, WTo, HID_, HID_);
    add(ao1_w, WTao1, D_, AH_);
    add(ao2_w, WTao2, AH_, D_);
    add(wo_e, WToe, 1024, 1024);
    ta.nseg = s;
    batch_transpose<<<dim3(blk), dim3(256), 0, stream>>>(ta);
  }

  // MFMA flash attention -> compact bf16 (text rows [0,ntext), entity at ntext_pad)
  attn_mfma<<<dim3(B_ * H_ * 16), dim3(256), 0, stream>>>(
      Q_bf, K_bf, VT_g, attn_bf, ttm, inv, cnt);

  // entity mean, then batch D: wo_t || adapter-out layer-1 (disjoint regions)
  //   seg0 R:{attn_bf 0-17.8M, WTo} W:{ct_out 50.3-67.1M}
  //   seg1 R:{oe_bf 17.8-22.0M, WTao1} W:{h1o 22.0-30.4M}
  mean_heads_kernel<<<dim3(NTOK * 1024 / 256), dim3(256), 0, stream>>>(attn_bf, oe_bf, cnt);
  {
    B b;
    b.add(attn_bf, WTo, nullptr, ct_out, NTOK, HID_, HID_, 0, 0, 1);
    b.add(oe_bf, WTao1, ao1_b, h1o, NTOK * 8, AH_, D_, 1, 0, 4);
    launch(b);
  }
  // serial tail of entity chain
  {
    B b; b.add(h1o, WTao2, ao2_b, oe2, NTOK * 8, D_, AH_, 0, 0, 4); launch(b);
  }
  {
    B b; b.add(oe2, WToe, nullptr, ce_out, NTOK, 1024, 1024, 0, 0, 3); launch(b);
  }

  // scatter to d_out with token-type masking
  scatter_out<<<dim3(NTOK), dim3(256), 0, stream>>>(
      ct_out, ce_out, ttm, inv, out_text, out_ent);
}

// Round 8
// 660.789 us; speedup vs baseline: 1.5654x; 1.0322x over previous
//
#include <hip/hip_runtime.h>
#include <cstdint>
#include <cstddef>

// Problem constants (reference: B=2,S=1024,HID=4096,H=32,D=128,KVH=8,EH=8,AH=256)
#define B_    2
#define S_    1024
#define HID_  4096
#define H_    32
#define D_    128
#define KVH_  8
#define EH_   8
#define AH_   256
#define NTOK  2048

typedef unsigned short u16;
typedef __attribute__((ext_vector_type(8))) short bf16x8;
typedef __attribute__((ext_vector_type(4))) float f32x4;
typedef const __attribute__((address_space(1))) void* gp_t;
typedef __attribute__((address_space(3))) void* lp_t;

__device__ __forceinline__ u16 f2bf(float f) {              // RNE f32->bf16
  unsigned u = __float_as_uint(f);
  return (u16)((u + 0x7FFF + ((u >> 16) & 1)) >> 16);
}
__device__ __forceinline__ float bf2f(u16 u) {
  return __uint_as_float((unsigned)u << 16);
}

// --------------- token-type scan: inv[] + counts (1 block) ---------------
// inv[t] = compact index within its type. cnt = {ntext, ntext_pad, nent,
// nent_pad, ceil128(nent*8), _}
__global__ __launch_bounds__(1024) void build_inv(
    const int* __restrict__ ttm, int* __restrict__ inv, int* __restrict__ cnt)
{
  __shared__ int a[NTOK], b[NTOK];
  const int t = threadIdx.x;
  for (int i = t; i < NTOK; i += 1024) a[i] = (ttm[i] != 1) ? 1 : 0;
  __syncthreads();
  int* src = a; int* dst = b;
  for (int off = 1; off < NTOK; off <<= 1) {
    for (int i = t; i < NTOK; i += 1024)
      dst[i] = src[i] + ((i >= off) ? src[i - off] : 0);
    __syncthreads();
    int* tmp = src; src = dst; dst = tmp;
  }
  for (int i = t; i < NTOK; i += 1024) {
    const int txt = (ttm[i] != 1);
    const int excl = src[i] - txt;
    inv[i] = txt ? excl : (i - excl);
  }
  if (t == 0) {
    const int ntext = src[NTOK - 1];
    const int nent = NTOK - ntext;
    cnt[0] = ntext;
    cnt[1] = (ntext + 127) & ~127;
    cnt[2] = nent;
    cnt[3] = (nent + 127) & ~127;
    cnt[4] = (nent * 8 + 127) & ~127;
  }
}

// --------------- gather inputs to per-type compact bf16 ---------------
__global__ __launch_bounds__(256) void gather_cast(
    const float* __restrict__ x_text, const float* __restrict__ x_ent,
    const int* __restrict__ ttm, const int* __restrict__ inv,
    u16* __restrict__ xt, u16* __restrict__ xe)
{
  const int tok = blockIdx.x;
  const int j = inv[tok];
  const int t = threadIdx.x;
  if (ttm[tok] != 1) {
    const float* src = x_text + (size_t)tok * HID_;
    u16* dst = xt + (size_t)j * HID_;
#pragma unroll
    for (int i = 0; i < 4; i++) {
      const int c = (i * 256 + t) * 4;
      const float4 v = *(const float4*)(src + c);
      ushort4 o; o.x = f2bf(v.x); o.y = f2bf(v.y); o.z = f2bf(v.z); o.w = f2bf(v.w);
      *(ushort4*)(dst + c) = o;
    }
  } else {
    const float* src = x_ent + (size_t)tok * 1024;
    u16* dst = xe + (size_t)j * 1024;
    const int c = t * 4;
    const float4 v = *(const float4*)(src + c);
    ushort4 o; o.x = f2bf(v.x); o.y = f2bf(v.y); o.z = f2bf(v.z); o.w = f2bf(v.w);
    *(ushort4*)(dst + c) = o;
  }
}

// ---------------- batched weight transpose+cast ----------------
struct TSeg { const float* W; u16* Wt; int K; int N; int blk0; };
struct TArgs { TSeg s[12]; int nseg; };

__global__ __launch_bounds__(256) void batch_transpose(TArgs args)
{
  int seg = 0;
#pragma unroll
  for (int i = 1; i < 12; i++)
    if (i < args.nseg && (int)blockIdx.x >= args.s[i].blk0) seg = i;
  const float* W = args.s[seg].W;
  u16* Wt = args.s[seg].Wt;
  const int K = args.s[seg].K, N = args.s[seg].N;
  const int local = blockIdx.x - args.s[seg].blk0;

  __shared__ float tle[32][33];
  const int tid = threadIdx.x;
  const int tx = tid & 31, ty = tid >> 5;
  const int nb = N >> 5;
  const int k0 = (local / nb) << 5;
  const int n0 = (local % nb) << 5;
#pragma unroll
  for (int r = 0; r < 32; r += 8)
    tle[ty + r][tx] = W[(size_t)(k0 + ty + r) * N + n0 + tx];
  __syncthreads();
#pragma unroll
  for (int r = 0; r < 32; r += 8)
    Wt[(size_t)(n0 + ty + r) * K + k0 + tx] = f2bf(tle[tx][ty + r]);
}

// --------------------- batched bf16 MFMA GEMM, 128x128 tile ---------------------
// m97 2-barrier K-loop. Segments concurrent: no output/input aliasing within
// one dispatch (r4 lesson).
//
// COALESCED STAGING (r6 diagnosis): lane->row mapping made every
// global_load_lds a 64-distinct-cache-line gather -> per-CU L1/TA transaction
// rate was the true bottleneck. Mapping: L = tid + inst*256, row = L>>2,
// chunk = L&3 -> 4 consecutive lanes read the four 16B chunks of ONE 64B
// row-line: 16 lines/instr. LDS row-major [128 rows][64 B]; fragment reads
// offset row*64 + lg*16 (measured conflict-free).
struct GSeg {
  const u16* A; const u16* Bt; const float* bias; u16* C;
  int N, K, act, astride, mlimIdx, blk0, nTM, nTN;
};
struct GArgs { GSeg s[4]; int nseg; };

__global__ __launch_bounds__(256) void gemm_batch(GArgs ga, const int* __restrict__ cnt)
{
  int seg = 0;
#pragma unroll
  for (int i = 1; i < 4; i++)
    if (i < ga.nseg && (int)blockIdx.x >= ga.s[i].blk0) seg = i;
  const GSeg sg = ga.s[seg];
  const int local = (int)blockIdx.x - sg.blk0;
  const int nTM = sg.nTM, nTN = sg.nTN;
  const int nwg = nTM * nTN;
  if (local >= nwg) return;                       // segment padding

  // bijective XCD swizzle (m204) + column-major tile order + row-stride perm
  const int xcd = local & 7, lix = local >> 3;
  const int q = nwg >> 3, rr_ = nwg & 7;
  const int wgid = (xcd < rr_ ? xcd * (q + 1) : rr_ * (q + 1) + (xcd - rr_) * q) + lix;
  const int tcol = wgid / nTM;
  int trow = wgid - tcol * nTM;
  if ((nTM & 7) == 0) trow = ((trow & 7) * (nTM >> 3)) + (trow >> 3);
  const int m0 = trow << 7;
  if (sg.mlimIdx >= 0 && m0 >= cnt[sg.mlimIdx]) return;
  const int n0 = tcol << 7;

  const int N = sg.N, K = sg.K;
  const u16* __restrict__ A = sg.A;
  const u16* __restrict__ Bt = sg.Bt;

  __shared__ __align__(16) char AsB[8192];   // [row 128][64 B] row-major
  __shared__ __align__(16) char BsB[8192];

  const int tid = threadIdx.x;
  const int wave = tid >> 6, lane = tid & 63;
  const int wm = ((wave >> 1) << 6);
  const int wn = ((wave & 1) << 6);
  const int l16 = lane & 15, lg = lane >> 4;

  // coalesced staging map: L = tid + inst*256; row = L>>2, chunk = L&3
  const int L0 = tid, L1 = tid + 256;
  const int r0 = L0 >> 2, g0 = L0 & 3;
  const int r1 = L1 >> 2, g1 = L1 & 3;

  auto arow = [&](int row) -> size_t {
    return sg.astride ? (size_t)(row >> 3) * sg.astride + (size_t)(row & 7) * K
                      : (size_t)row * K;
  };
  const u16* a0 = A + arow(m0 + r0) + g0 * 8;
  const u16* a1 = A + arow(m0 + r1) + g1 * 8;
  const u16* b0 = Bt + (size_t)(n0 + r0) * K + g0 * 8;
  const u16* b1 = Bt + (size_t)(n0 + r1) * K + g1 * 8;

  // LDS dest bases (HW adds lane*16): offset(L) = L*16 = wave*1024 + lane*16 (+ inst*4096)
  const int dst0 = wave * 1024;
  const int dst1 = wave * 1024 + 4096;

  f32x4 acc[4][4];
#pragma unroll
  for (int i = 0; i < 4; i++)
#pragma unroll
    for (int j = 0; j < 4; j++) acc[i][j] = (f32x4)0.f;

  for (int k0 = 0; k0 < K; k0 += 32) {
    if (k0) __syncthreads();
    __builtin_amdgcn_global_load_lds((gp_t)a0, (lp_t)(AsB + dst0), 16, 0, 0);
    __builtin_amdgcn_global_load_lds((gp_t)a1, (lp_t)(AsB + dst1), 16, 0, 0);
    __builtin_amdgcn_global_load_lds((gp_t)b0, (lp_t)(BsB + dst0), 16, 0, 0);
    __builtin_amdgcn_global_load_lds((gp_t)b1, (lp_t)(BsB + dst1), 16, 0, 0);
    a0 += 32; a1 += 32; b0 += 32; b1 += 32;
    __syncthreads();

    bf16x8 af[4], bv[4];
#pragma unroll
    for (int i = 0; i < 4; i++)
      af[i] = *(const bf16x8*)(AsB + (wm + 16 * i + l16) * 64 + lg * 16);
#pragma unroll
    for (int j = 0; j < 4; j++)
      bv[j] = *(const bf16x8*)(BsB + (wn + 16 * j + l16) * 64 + lg * 16);
#pragma unroll
    for (int i = 0; i < 4; i++)
#pragma unroll
      for (int j = 0; j < 4; j++)
        acc[i][j] = __builtin_amdgcn_mfma_f32_16x16x32_bf16(af[i], bv[j], acc[i][j], 0, 0, 0);
  }

  // epilogue: C/D map col=lane&15, row=(lane>>4)*4+reg
#pragma unroll
  for (int i = 0; i < 4; i++) {
#pragma unroll
    for (int r = 0; r < 4; r++) {
      const int row = m0 + wm + 16 * i + lg * 4 + r;
#pragma unroll
      for (int j = 0; j < 4; j++) {
        const int col = n0 + wn + 16 * j + l16;
        float c = acc[i][j][r];
        if (sg.bias) c += sg.bias[col];
        if (sg.act) c = 0.5f * c * (1.f + erff(c * 0.70710678118654752f));  // exact GELU
        sg.C[(size_t)row * N + col] = f2bf(c);
      }
    }
  }
}

// ------------- select + RoPE -> bf16 Q (prescaled), bf16 K (full token index) -------------
__global__ __launch_bounds__(256) void select_rope_bf(
    const u16* __restrict__ qkv, const u16* __restrict__ qe,
    const u16* __restrict__ ke, u16* __restrict__ Qb, u16* __restrict__ Kb,
    const int* __restrict__ ttm, const int* __restrict__ inv,
    const int* __restrict__ pid)
{
  __shared__ float cs[64], sn[64];
  const int token = blockIdx.x;
  const bool is_e = (ttm[token] == 1);
  const int j = inv[token];
  const int t = threadIdx.x;
  if (t < 64) {
    const float pos = (float)pid[token];
    const float iv = __expf(-((float)(2 * t) * (1.f / 128.f)) * 9.210340371976184f);
    const float f = pos * iv;
    cs[t] = cosf(f); sn[t] = sinf(f);
  }
  __syncthreads();
  const float scale = 0.08838834764831845f;  // 1/sqrt(128) folded into Q
  const u16* qrow = qkv + (size_t)j * 6144;

  for (int it = t; it < H_ * 64; it += 256) {
    const int h = it >> 6, i = it & 63;
    float x1, x2;
    if (is_e) {
      const size_t eb = ((size_t)j * 8 + (h & 7)) * D_;
      x1 = bf2f(qe[eb + i]); x2 = bf2f(qe[eb + i + 64]);
    } else {
      x1 = bf2f(qrow[h * 128 + i]); x2 = bf2f(qrow[h * 128 + i + 64]);
    }
    const size_t base = ((size_t)token * H_ + h) * D_;
    Qb[base + i]      = f2bf((x1 * cs[i] - x2 * sn[i]) * scale);
    Qb[base + i + 64] = f2bf((x2 * cs[i] + x1 * sn[i]) * scale);
  }
  for (int it = t; it < KVH_ * 64; it += 256) {
    const int h = it >> 6, i = it & 63;
    float x1, x2;
    if (is_e) {
      const size_t eb = ((size_t)j * 8 + h) * D_;
      x1 = bf2f(ke[eb + i]); x2 = bf2f(ke[eb + i + 64]);
    } else {
      x1 = bf2f(qrow[4096 + h * 128 + i]); x2 = bf2f(qrow[4096 + h * 128 + i + 64]);
    }
    const size_t base = ((size_t)token * KVH_ + h) * D_;
    Kb[base + i]      = f2bf(x1 * cs[i] - x2 * sn[i]);
    Kb[base + i + 64] = f2bf(x2 * cs[i] + x1 * sn[i]);
  }
}

// ---------- V select + transpose: VT[b][hk][d][s] bf16 ----------
__global__ __launch_bounds__(256) void vtrans_kernel(
    const u16* __restrict__ qkv, const u16* __restrict__ ve,
    const int* __restrict__ ttm, const int* __restrict__ inv,
    u16* __restrict__ VTg)
{
  __shared__ float t[32][33];
  const int dt = blockIdx.x & 3;
  const int st = (blockIdx.x >> 2) & 31;
  const int hk = (blockIdx.x >> 7) & 7;
  const int b  = blockIdx.x >> 10;
  const int s0 = st * 32, d0 = dt * 32;
  const int tx = threadIdx.x & 31, ty = threadIdx.x >> 5;
#pragma unroll
  for (int i = 0; i < 4; i++) {
    const int r = ty + 8 * i;
    const int tok = b * S_ + s0 + r;
    const int j = inv[tok];
    t[r][tx] = (ttm[tok] == 1)
        ? bf2f(ve[((size_t)j * 8 + hk) * D_ + d0 + tx])
        : bf2f(qkv[(size_t)j * 6144 + 5120 + hk * 128 + d0 + tx]);
  }
  __syncthreads();
#pragma unroll
  for (int i = 0; i < 4; i++) {
    const int rr = ty + 8 * i;
    VTg[((size_t)(b * KVH_ + hk) * D_ + d0 + rr) * S_ + s0 + tx] = f2bf(t[tx][rr]);
  }
}

// ------------------- MFMA causal GQA flash attention (compact output) -------------------
// COALESCED STAGING + XOR-swizzled LDS (r7 diagnosis: K/V staging had the
// same 64-distinct-line gather disease as the r6 GEMM -- lanes strided by
// 2048B, 16B/line; ~512 line transactions per tile was the critical path,
// MfmaUtil 5%).
//   K tile LDS: [key 64][chunk 16][16B], chunk XOR (key&15). Load L=i*256+tid,
//     key=L>>4, ch=L&15 -> 16 lanes read one contiguous 256B K-row (16 lines
//     per instr, 4x fewer). Write contiguous-permuted per row; read balanced
//     8 words/bank (same class the GEMM measures conflict-free).
//   V tile LDS: [d 128][chunk 8][16B], chunk XOR (d&7). Load d=L>>3, ch=L&7
//     -> 8 lanes read one contiguous 128B VT-row.
__global__ __launch_bounds__(256) void attn_mfma(
    const u16* __restrict__ Qb, const u16* __restrict__ Kb,
    const u16* __restrict__ VTg, u16* __restrict__ O,
    const int* __restrict__ ttm, const int* __restrict__ inv,
    const int* __restrict__ cnt)
{
  __shared__ __align__(16) u16 Ks[64 * 16 * 8];     // [key][chunk^swz][8]
  __shared__ __align__(16) u16 VTs[128 * 8 * 8];    // [d][chunk^swz][8]
  __shared__ __align__(16) float Ps[4][16 * 68];

  const int tid = threadIdx.x;
  const int wave = tid >> 6, lane = tid & 63;
  const int l16 = lane & 15, lg = lane >> 4;

  const int qtile = 15 - (blockIdx.x & 15);
  const int h = (blockIdx.x >> 4) & (H_ - 1);
  const int b = blockIdx.x >> 9;
  const int q0 = qtile * 64;
  const int hk = h & 7;
  const int qw = q0 + 16 * wave;
  const int qmax = qw + 15;

  bf16x8 qf[4];
  {
    const u16* qrow = Qb + ((size_t)(b * S_ + qw + l16) * H_ + h) * D_;
#pragma unroll
    for (int c = 0; c < 4; c++)
      qf[c] = *(const bf16x8*)(qrow + c * 32 + lg * 8);
  }

  f32x4 o[8];
#pragma unroll
  for (int nt = 0; nt < 8; nt++) o[nt] = (f32x4)0.f;
  float mrun[4] = {-1e30f, -1e30f, -1e30f, -1e30f};
  float lrun[4] = {0.f, 0.f, 0.f, 0.f};

  const int ntiles = qtile + 1;
  for (int t = 0; t < ntiles; t++) {
    const int k0 = t * 64;
    if (t) __syncthreads();
    // K stage: coalesced (16 lanes per 256B key-row), swizzled LDS
#pragma unroll
    for (int i = 0; i < 4; i++) {
      const int L = i * 256 + tid;
      const int key = L >> 4, ch = L & 15;
      *(bf16x8*)(Ks + (size_t)key * 128 + ((ch ^ (key & 15)) * 8)) =
          *(const bf16x8*)(Kb + ((size_t)(b * S_ + k0 + key) * KVH_ + hk) * D_ + ch * 8);
    }
    // V stage: coalesced (8 lanes per 128B d-row), swizzled LDS
#pragma unroll
    for (int i = 0; i < 4; i++) {
      const int L = i * 256 + tid;
      const int d = L >> 3, ch = L & 7;
      *(bf16x8*)(VTs + (size_t)d * 64 + ((ch ^ (d & 7)) * 8)) =
          *(const bf16x8*)(VTg + ((size_t)(b * KVH_ + hk) * D_ + d) * S_ + k0 + ch * 8);
    }
    __syncthreads();

    if (k0 > qmax) continue;

    f32x4 s[4];
#pragma unroll
    for (int c = 0; c < 4; c++) s[c] = (f32x4)0.f;
#pragma unroll
    for (int c = 0; c < 4; c++)
#pragma unroll
      for (int dc = 0; dc < 4; dc++) {
        const bf16x8 kf = *(const bf16x8*)(
            Ks + (size_t)(c * 16 + l16) * 128 + (((dc * 4 + lg) ^ l16) * 8));
        s[c] = __builtin_amdgcn_mfma_f32_16x16x32_bf16(qf[dc], kf, s[c], 0, 0, 0);
      }

    float p[4][4], alpha[4];
#pragma unroll
    for (int r = 0; r < 4; r++) {
      const int qg = qw + lg * 4 + r;
      float sv[4], mx = -1e30f;
#pragma unroll
      for (int c = 0; c < 4; c++) {
        const int kg_ = k0 + c * 16 + l16;
        float v = (kg_ <= qg) ? s[c][r] : -1e30f;
        sv[c] = v;
        mx = fmaxf(mx, v);
      }
#pragma unroll
      for (int off = 1; off < 16; off <<= 1)
        mx = fmaxf(mx, __shfl_xor(mx, off));
      const float mn = fmaxf(mrun[r], mx);
      alpha[r] = __expf(mrun[r] - mn);
      mrun[r] = mn;
      float rs = 0.f;
#pragma unroll
      for (int c = 0; c < 4; c++) { p[c][r] = __expf(sv[c] - mn); rs += p[c][r]; }
#pragma unroll
      for (int off = 1; off < 16; off <<= 1)
        rs += __shfl_xor(rs, off);
      lrun[r] = lrun[r] * alpha[r] + rs;
    }
#pragma unroll
    for (int nt = 0; nt < 8; nt++)
#pragma unroll
      for (int r = 0; r < 4; r++) o[nt][r] *= alpha[r];

    float* pw = Ps[wave];
#pragma unroll
    for (int c = 0; c < 4; c++)
#pragma unroll
      for (int r = 0; r < 4; r++)
        pw[(lg * 4 + r) * 68 + c * 16 + l16] = p[c][r];

    bf16x8 pa[2];
#pragma unroll
    for (int kc = 0; kc < 2; kc++) {
      const float* src = pw + l16 * 68 + kc * 32 + lg * 8;
      const float4 f0 = *(const float4*)(src);
      const float4 f1 = *(const float4*)(src + 4);
      bf16x8 v;
      v[0] = (short)f2bf(f0.x); v[1] = (short)f2bf(f0.y);
      v[2] = (short)f2bf(f0.z); v[3] = (short)f2bf(f0.w);
      v[4] = (short)f2bf(f1.x); v[5] = (short)f2bf(f1.y);
      v[6] = (short)f2bf(f1.z); v[7] = (short)f2bf(f1.w);
      pa[kc] = v;
    }

#pragma unroll
    for (int nt = 0; nt < 8; nt++)
#pragma unroll
      for (int kc = 0; kc < 2; kc++) {
        const bf16x8 vf = *(const bf16x8*)(
            VTs + (size_t)(nt * 16 + l16) * 64 + (((kc * 4 + lg) ^ (l16 & 7)) * 8));
        o[nt] = __builtin_amdgcn_mfma_f32_16x16x32_bf16(pa[kc], vf, o[nt], 0, 0, 0);
      }
  }

  // epilogue -> compact row: text j, entity ntext_pad + j
  const int ntext_pad = cnt[1];
#pragma unroll
  for (int r = 0; r < 4; r++) {
    const float inv_l = 1.f / lrun[r];
    const int tok = b * S_ + qw + lg * 4 + r;
    const int j = inv[tok];
    const int crow = (ttm[tok] != 1) ? j : (ntext_pad + j);
    u16* orow = O + (size_t)crow * (H_ * D_) + h * D_ + l16;
#pragma unroll
    for (int nt = 0; nt < 8; nt++)
      orow[nt * 16] = f2bf(o[nt][r] * inv_l);
  }
}

// ------------------- mean over 4 head-replicas (entity-compact) -------------------
__global__ __launch_bounds__(256) void mean_heads_kernel(
    const u16* __restrict__ attn, u16* __restrict__ oe, const int* __restrict__ cnt)
{
  const size_t idx = (size_t)blockIdx.x * 256 + threadIdx.x;
  const int j = (int)(idx >> 10);
  if (j >= cnt[2]) return;
  const int r = (int)(idx & 1023);
  const int h = r >> 7, d = r & 127;
  const u16* a = attn + (size_t)(cnt[1] + j) * (H_ * D_);
  const float s = 0.25f * (bf2f(a[h * D_ + d]) + bf2f(a[(8 + h) * D_ + d]) +
                           bf2f(a[(16 + h) * D_ + d]) + bf2f(a[(24 + h) * D_ + d]));
  oe[idx] = f2bf(s);
}

// ------------------- scatter compact outs -> d_out with type masking -------------------
__global__ __launch_bounds__(256) void scatter_out(
    const u16* __restrict__ ct, const u16* __restrict__ ce,
    const int* __restrict__ ttm, const int* __restrict__ inv,
    float* __restrict__ out_text, float* __restrict__ out_ent)
{
  const int tok = blockIdx.x;
  const bool is_e = (ttm[tok] == 1);
  const int j = inv[tok];
  const int t = threadIdx.x;
  float* ot = out_text + (size_t)tok * HID_;
#pragma unroll
  for (int i = 0; i < 4; i++) {
    const int c = (i * 256 + t) * 4;
    float4 v = make_float4(0.f, 0.f, 0.f, 0.f);
    if (!is_e) {
      const ushort4 u = *(const ushort4*)(ct + (size_t)j * HID_ + c);
      v.x = bf2f(u.x); v.y = bf2f(u.y); v.z = bf2f(u.z); v.w = bf2f(u.w);
    }
    *(float4*)(ot + c) = v;
  }
  float* oe_ = out_ent + (size_t)tok * 1024;
  {
    const int c = t * 4;
    float4 v = make_float4(0.f, 0.f, 0.f, 0.f);
    if (is_e) {
      const ushort4 u = *(const ushort4*)(ce + (size_t)j * 1024 + c);
      v.x = bf2f(u.x); v.y = bf2f(u.y); v.z = bf2f(u.z); v.w = bf2f(u.w);
    }
    *(float4*)(oe_ + c) = v;
  }
}

// ------------------------------- launcher -------------------------------
extern "C" void kernel_launch(void* const* d_in, const int* in_sizes, int n_in,
                              void* d_out, int out_size, void* d_ws, size_t ws_size,
                              hipStream_t stream)
{
  const float* x_text = (const float*)d_in[0];
  const float* x_ent  = (const float*)d_in[1];
  const float* wq_t   = (const float*)d_in[2];
  const float* wk_t   = (const float*)d_in[3];
  const float* wv_t   = (const float*)d_in[4];
  const float* wo_t   = (const float*)d_in[5];
  const float* wq_e   = (const float*)d_in[6];
  const float* wk_e   = (const float*)d_in[7];
  const float* wv_e   = (const float*)d_in[8];
  const float* wo_e   = (const float*)d_in[9];
  const float* aq1_w = (const float*)d_in[10]; const float* aq1_b = (const float*)d_in[11];
  const float* aq2_w = (const float*)d_in[12]; const float* aq2_b = (const float*)d_in[13];
  const float* ak1_w = (const float*)d_in[14]; const float* ak1_b = (const float*)d_in[15];
  const float* ak2_w = (const float*)d_in[16]; const float* ak2_b = (const float*)d_in[17];
  const float* av1_w = (const float*)d_in[18]; const float* av1_b = (const float*)d_in[19];
  const float* av2_w = (const float*)d_in[20]; const float* av2_b = (const float*)d_in[21];
  const float* ao1_w = (const float*)d_in[22]; const float* ao1_b = (const float*)d_in[23];
  const float* ao2_w = (const float*)d_in[24]; const float* ao2_b = (const float*)d_in[25];
  const int*   ttm   = (const int*)d_in[27];
  const int*   pid   = (const int*)d_in[28];

  float* out_text = (float*)d_out;                       // [2048,4096]
  float* out_ent  = out_text + (size_t)B_ * S_ * HID_;   // [2048,1024]

  // ---- workspace layout (bytes), peak ~132.5 MB ----
  // Liveness audit (r4/r5): e_all at 25,165,824 over the qe/ke/ve span.
  // e_all live [batchA.W -> batchB.R]; qe/ke/ve live [batchC.W -> rope/vtrans.R].
  char* w = (char*)d_ws;
  u16*   qkv_bf = (u16*)(w + 0);             // 25,165,824  [2048][6144] compact text
  u16*   e_all  = (u16*)(w + 25165824);      // 12,582,912  [2048][3072] compact ent (batch A-B)
  u16*   qe     = (u16*)(w + 25165824);      //  4,194,304  [2048*8][128] (batch C+)
  u16*   ke     = (u16*)(w + 29360128);      //  4,194,304
  u16*   ve     = (u16*)(w + 33554432);      //  4,194,304
  u16*   h1q    = (u16*)(w + 37748736);      //  8,388,608  [16384][256]
  u16*   attn_bf = (u16*)(w + 0);            // 17,825,792  [2176][4096] compact
  u16*   oe_bf   = (u16*)(w + 17825792);     //  4,194,304
  u16*   h1o     = (u16*)(w + 22020096);     //  8,388,608
  u16*   oe2     = (u16*)(w + 30408704);     //  4,194,304
  u16*   xt_bf = (u16*)(w + 50331648);       // 16,777,216  [2048][4096] compact text
  u16*   Q_bf  = (u16*)(w + 50331648);       // 16,777,216  full-token
  u16*   ct_out = (u16*)(w + 50331648);      // 16,777,216  wo_t compact C
  u16*   h1k   = (u16*)(w + 62914560);       //  8,388,608  (62.9MB..71.3MB)
  u16*   xe_bf = (u16*)(w + 67108864);       //  4,194,304  [2048][1024] compact ent
  u16*   K_bf  = (u16*)(w + 67108864);       //  4,194,304  full-token
  u16*   ce_out = (u16*)(w + 67108864);      //  4,194,304  wo_e compact C
  u16*   WTb   = (u16*)(w + 71303168);       // 50,331,648  [6144][4096]
  u16*   h1v   = (u16*)(w + 71303168);       //  8,388,608  (over dead WTb, pre-WTo)
  u16*   WTo   = (u16*)(w + 71303168);       // 33,554,432  [4096][4096]
  u16*   WTao1 = (u16*)(w + 104857600);      //     65,536
  u16*   WTao2 = (u16*)(w + 104923136);      //     65,536
  u16*   WToe  = (u16*)(w + 104988672);      //  2,097,152
  u16*   WTe   = (u16*)(w + 121634816);      //  6,291,456  [3072][1024]
  u16*   WTa   = (u16*)(w + 127926272);      //    393,216  6 x [.][.]
  u16*   VT_g  = (u16*)(w + 128319488);      //  4,194,304
  int*   inv   = (int*)(w + 132513792);      //      8,192
  int*   cnt   = (int*)(w + 132521984);      //         64

  // batched GEMM launcher: segments padded to %8 blocks
  struct B {
    GArgs ga{}; int blk = 0;
    void add(const u16* A, const u16* Bt, const float* bias, u16* C,
             int M, int N, int K, int act, int astride, int mlimIdx) {
      GSeg& s = ga.s[ga.nseg++];
      s = {A, Bt, bias, C, N, K, act, astride, mlimIdx, blk, M >> 7, N >> 7};
      blk += ((s.nTM * s.nTN) + 7) & ~7;
    }
  };
  auto launch = [&](B& b) {
    gemm_batch<<<dim3(b.blk), dim3(256), 0, stream>>>(b.ga, cnt);
  };

  // weight transposes, batch 1 (everything pre-attention)
  {
    TArgs ta{}; int blk = 0, s = 0;
    auto add = [&](const float* W, u16* Wt, int K, int N) {
      ta.s[s] = {W, Wt, K, N, blk}; blk += (K >> 5) * (N >> 5); s++;
    };
    add(wq_t, WTb, HID_, HID_);
    add(wk_t, WTb + (size_t)4096 * HID_, HID_, 1024);
    add(wv_t, WTb + (size_t)5120 * HID_, HID_, 1024);
    add(wq_e, WTe, 1024, 1024);
    add(wk_e, WTe + (size_t)1024 * 1024, 1024, 1024);
    add(wv_e, WTe + (size_t)2048 * 1024, 1024, 1024);
    add(aq1_w, WTa,          D_, AH_);
    add(aq2_w, WTa + 32768,  AH_, D_);
    add(ak1_w, WTa + 65536,  D_, AH_);
    add(ak2_w, WTa + 98304,  AH_, D_);
    add(av1_w, WTa + 131072, D_, AH_);
    add(av2_w, WTa + 163840, AH_, D_);
    ta.nseg = s;
    batch_transpose<<<dim3(blk), dim3(256), 0, stream>>>(ta);
  }

  // token-type scan + input gather
  build_inv<<<dim3(1), dim3(1024), 0, stream>>>(ttm, inv, cnt);
  gather_cast<<<dim3(NTOK), dim3(256), 0, stream>>>(x_text, x_ent, ttm, inv, xt_bf, xe_bf);

  // batch A: text QKV || entity projection (disjoint regions)
  //   seg0 R:{xt_bf,WTb} W:{qkv_bf}   seg1 R:{xe_bf,WTe} W:{e_all@25.2MB}
  {
    B b;
    b.add(xt_bf, WTb, nullptr, qkv_bf, NTOK, 6144, HID_, 0, 0, 1);
    b.add(xe_bf, WTe, nullptr, e_all, NTOK, 3072, 1024, 0, 0, 3);
    launch(b);
  }
  // batch B: adapter layer-1 q||k||v (share input e_all; outputs disjoint)
  {
    B b;
    b.add(e_all,        WTa,          aq1_b, h1q, NTOK * 8, AH_, D_, 1, 3072, 4);
    b.add(e_all + 1024, WTa + 65536,  ak1_b, h1k, NTOK * 8, AH_, D_, 1, 3072, 4);
    b.add(e_all + 2048, WTa + 131072, av1_b, h1v, NTOK * 8, AH_, D_, 1, 3072, 4);
    launch(b);
  }
  // batch C: adapter layer-2 q||k||v (write qe/ke/ve over dead e_all)
  {
    B b;
    b.add(h1q, WTa + 32768,  aq2_b, qe, NTOK * 8, D_, AH_, 0, 0, 4);
    b.add(h1k, WTa + 98304,  ak2_b, ke, NTOK * 8, D_, AH_, 0, 0, 4);
    b.add(h1v, WTa + 163840, av2_b, ve, NTOK * 8, D_, AH_, 0, 0, 4);
    launch(b);
  }

  // select + RoPE -> full-token Q/K bf16; V transpose
  select_rope_bf<<<dim3(NTOK), dim3(256), 0, stream>>>(
      qkv_bf, qe, ke, Q_bf, K_bf, ttm, inv, pid);
  vtrans_kernel<<<dim3(B_ * KVH_ * 32 * 4), dim3(256), 0, stream>>>(
      qkv_bf, ve, ttm, inv, VT_g);

  // weight transposes, batch 2 (into dead WTb region; h1v already consumed)
  {
    TArgs ta{}; int blk = 0, s = 0;
    auto add = [&](const float* W, u16* Wt, int K, int N) {
      ta.s[s] = {W, Wt, K, N, blk}; blk += (K >> 5) * (N >> 5); s++;
    };
    add(wo_t, WTo, HID_, HID_);
    add(ao1_w, WTao1, D_, AH_);
    add(ao2_w, WTao2, AH_, D_);
    add(wo_e, WToe, 1024, 1024);
    ta.nseg = s;
    batch_transpose<<<dim3(blk), dim3(256), 0, stream>>>(ta);
  }

  // MFMA flash attention -> compact bf16 (text rows [0,ntext), entity at ntext_pad)
  attn_mfma<<<dim3(B_ * H_ * 16), dim3(256), 0, stream>>>(
      Q_bf, K_bf, VT_g, attn_bf, ttm, inv, cnt);

  // entity mean, then batch D: wo_t || adapter-out layer-1 (disjoint regions)
  //   seg0 R:{attn_bf 0-17.8M, WTo} W:{ct_out 50.3-67.1M}
  //   seg1 R:{oe_bf 17.8-22.0M, WTao1} W:{h1o 22.0-30.4M}
  mean_heads_kernel<<<dim3(NTOK * 1024 / 256), dim3(256), 0, stream>>>(attn_bf, oe_bf, cnt);
  {
    B b;
    b.add(attn_bf, WTo, nullptr, ct_out, NTOK, HID_, HID_, 0, 0, 1);
    b.add(oe_bf, WTao1, ao1_b, h1o, NTOK * 8, AH_, D_, 1, 0, 4);
    launch(b);
  }
  // serial tail of entity chain
  {
    B b; b.add(h1o, WTao2, ao2_b, oe2, NTOK * 8, D_, AH_, 0, 0, 4); launch(b);
  }
  {
    B b; b.add(oe2, WToe, nullptr, ce_out, NTOK, 1024, 1024, 0, 0, 3); launch(b);
  }

  // scatter to d_out with token-type masking
  scatter_out<<<dim3(NTOK), dim3(256), 0, stream>>>(
      ct_out, ce_out, ttm, inv, out_text, out_ent);
}

// Round 9
// 653.167 us; speedup vs baseline: 1.5836x; 1.0117x over previous
//
#include <hip/hip_runtime.h>
#include <cstdint>
#include <cstddef>

// Problem constants (reference: B=2,S=1024,HID=4096,H=32,D=128,KVH=8,EH=8,AH=256)
#define B_    2
#define S_    1024
#define HID_  4096
#define H_    32
#define D_    128
#define KVH_  8
#define EH_   8
#define AH_   256
#define NTOK  2048

typedef unsigned short u16;
typedef __attribute__((ext_vector_type(8))) short bf16x8;
typedef __attribute__((ext_vector_type(4))) float f32x4;
typedef const __attribute__((address_space(1))) void* gp_t;
typedef __attribute__((address_space(3))) void* lp_t;

__device__ __forceinline__ u16 f2bf(float f) {              // RNE f32->bf16
  unsigned u = __float_as_uint(f);
  return (u16)((u + 0x7FFF + ((u >> 16) & 1)) >> 16);
}
__device__ __forceinline__ float bf2f(u16 u) {
  return __uint_as_float((unsigned)u << 16);
}

// --------------- token-type scan: inv[] + counts (1 block) ---------------
// inv[t] = compact index within its type. cnt = {ntext, ntext_pad, nent,
// nent_pad, ceil128(nent*8), _}
__global__ __launch_bounds__(1024) void build_inv(
    const int* __restrict__ ttm, int* __restrict__ inv, int* __restrict__ cnt)
{
  __shared__ int a[NTOK], b[NTOK];
  const int t = threadIdx.x;
  for (int i = t; i < NTOK; i += 1024) a[i] = (ttm[i] != 1) ? 1 : 0;
  __syncthreads();
  int* src = a; int* dst = b;
  for (int off = 1; off < NTOK; off <<= 1) {
    for (int i = t; i < NTOK; i += 1024)
      dst[i] = src[i] + ((i >= off) ? src[i - off] : 0);
    __syncthreads();
    int* tmp = src; src = dst; dst = tmp;
  }
  for (int i = t; i < NTOK; i += 1024) {
    const int txt = (ttm[i] != 1);
    const int excl = src[i] - txt;
    inv[i] = txt ? excl : (i - excl);
  }
  if (t == 0) {
    const int ntext = src[NTOK - 1];
    const int nent = NTOK - ntext;
    cnt[0] = ntext;
    cnt[1] = (ntext + 127) & ~127;
    cnt[2] = nent;
    cnt[3] = (nent + 127) & ~127;
    cnt[4] = (nent * 8 + 127) & ~127;
  }
}

// --------------- gather inputs to per-type compact bf16 ---------------
__global__ __launch_bounds__(256) void gather_cast(
    const float* __restrict__ x_text, const float* __restrict__ x_ent,
    const int* __restrict__ ttm, const int* __restrict__ inv,
    u16* __restrict__ xt, u16* __restrict__ xe)
{
  const int tok = blockIdx.x;
  const int j = inv[tok];
  const int t = threadIdx.x;
  if (ttm[tok] != 1) {
    const float* src = x_text + (size_t)tok * HID_;
    u16* dst = xt + (size_t)j * HID_;
#pragma unroll
    for (int i = 0; i < 4; i++) {
      const int c = (i * 256 + t) * 4;
      const float4 v = *(const float4*)(src + c);
      ushort4 o; o.x = f2bf(v.x); o.y = f2bf(v.y); o.z = f2bf(v.z); o.w = f2bf(v.w);
      *(ushort4*)(dst + c) = o;
    }
  } else {
    const float* src = x_ent + (size_t)tok * 1024;
    u16* dst = xe + (size_t)j * 1024;
    const int c = t * 4;
    const float4 v = *(const float4*)(src + c);
    ushort4 o; o.x = f2bf(v.x); o.y = f2bf(v.y); o.z = f2bf(v.z); o.w = f2bf(v.w);
    *(ushort4*)(dst + c) = o;
  }
}

// ---------------- batched weight transpose+cast ----------------
struct TSeg { const float* W; u16* Wt; int K; int N; int blk0; };
struct TArgs { TSeg s[12]; int nseg; };

__global__ __launch_bounds__(256) void batch_transpose(TArgs args)
{
  int seg = 0;
#pragma unroll
  for (int i = 1; i < 12; i++)
    if (i < args.nseg && (int)blockIdx.x >= args.s[i].blk0) seg = i;
  const float* W = args.s[seg].W;
  u16* Wt = args.s[seg].Wt;
  const int K = args.s[seg].K, N = args.s[seg].N;
  const int local = blockIdx.x - args.s[seg].blk0;

  __shared__ float tle[32][33];
  const int tid = threadIdx.x;
  const int tx = tid & 31, ty = tid >> 5;
  const int nb = N >> 5;
  const int k0 = (local / nb) << 5;
  const int n0 = (local % nb) << 5;
#pragma unroll
  for (int r = 0; r < 32; r += 8)
    tle[ty + r][tx] = W[(size_t)(k0 + ty + r) * N + n0 + tx];
  __syncthreads();
#pragma unroll
  for (int r = 0; r < 32; r += 8)
    Wt[(size_t)(n0 + ty + r) * K + k0 + tx] = f2bf(tle[tx][ty + r]);
}

// --------------------- batched bf16 MFMA GEMM, 128x128 tile ---------------------
// m97 2-barrier K-loop. Segments concurrent: no output/input aliasing within
// one dispatch (r4 lesson).
//
// COALESCED STAGING (r6/r7): L = tid + inst*256, row = L>>2 -> 4 consecutive
// lanes cover one 64B row-line (16 lines/instr; fixed the per-CU line-
// transaction bottleneck, 826->682us).
//
// XOR CHUNK SWIZZLE (r8 fix): r7's linear [row][64B] layout made fragment
// ds_read_b128 a 4-8-way bank conflict (row*16 words mod 32 collapses 16 rows
// into 2 bank-groups; SQ_LDS_BANK_CONFLICT 0 -> 7.2M). Swizzle s=(row>>1)&3:
// staging lane loads global chunk (slot ^ s) -- XOR permutes WITHIN the 64B
// line so coalescing is unchanged -- and the fragment read fetches chunk lg
// at slot (lg ^ s). Read banks: (l16&1)*16 + ((lg^((l16>>1)&3))&3)*4 -> 16
// lanes over 8 bank-groups = 2-way = free (m136). Same involution on both
// sides (rule 21).
struct GSeg {
  const u16* A; const u16* Bt; const float* bias; u16* C;
  int N, K, act, astride, mlimIdx, blk0, nTM, nTN;
};
struct GArgs { GSeg s[4]; int nseg; };

__global__ __launch_bounds__(256) void gemm_batch(GArgs ga, const int* __restrict__ cnt)
{
  int seg = 0;
#pragma unroll
  for (int i = 1; i < 4; i++)
    if (i < ga.nseg && (int)blockIdx.x >= ga.s[i].blk0) seg = i;
  const GSeg sg = ga.s[seg];
  const int local = (int)blockIdx.x - sg.blk0;
  const int nTM = sg.nTM, nTN = sg.nTN;
  const int nwg = nTM * nTN;
  if (local >= nwg) return;                       // segment padding

  // bijective XCD swizzle (m204) + column-major tile order + row-stride perm
  const int xcd = local & 7, lix = local >> 3;
  const int q = nwg >> 3, rr_ = nwg & 7;
  const int wgid = (xcd < rr_ ? xcd * (q + 1) : rr_ * (q + 1) + (xcd - rr_) * q) + lix;
  const int tcol = wgid / nTM;
  int trow = wgid - tcol * nTM;
  if ((nTM & 7) == 0) trow = ((trow & 7) * (nTM >> 3)) + (trow >> 3);
  const int m0 = trow << 7;
  if (sg.mlimIdx >= 0 && m0 >= cnt[sg.mlimIdx]) return;
  const int n0 = tcol << 7;

  const int N = sg.N, K = sg.K;
  const u16* __restrict__ A = sg.A;
  const u16* __restrict__ Bt = sg.Bt;

  __shared__ __align__(16) char AsB[8192];   // [row 128][chunk^swz 4][16B]
  __shared__ __align__(16) char BsB[8192];

  const int tid = threadIdx.x;
  const int wave = tid >> 6, lane = tid & 63;
  const int wm = ((wave >> 1) << 6);
  const int wn = ((wave & 1) << 6);
  const int l16 = lane & 15, lg = lane >> 4;

  // coalesced staging map with XOR chunk swizzle
  const int L0 = tid, L1 = tid + 256;
  const int r0 = L0 >> 2, g0 = (L0 & 3) ^ ((r0 >> 1) & 3);
  const int r1 = L1 >> 2, g1 = (L1 & 3) ^ ((r1 >> 1) & 3);

  auto arow = [&](int row) -> size_t {
    return sg.astride ? (size_t)(row >> 3) * sg.astride + (size_t)(row & 7) * K
                      : (size_t)row * K;
  };
  const u16* a0 = A + arow(m0 + r0) + g0 * 8;
  const u16* a1 = A + arow(m0 + r1) + g1 * 8;
  const u16* b0 = Bt + (size_t)(n0 + r0) * K + g0 * 8;
  const u16* b1 = Bt + (size_t)(n0 + r1) * K + g1 * 8;

  // LDS dest bases (HW adds lane*16): offset(L) = L*16 = wave*1024 + lane*16 (+ inst*4096)
  const int dst0 = wave * 1024;
  const int dst1 = wave * 1024 + 4096;

  // fragment-read chunk slot for global chunk lg at row r: slot = lg ^ ((r>>1)&3);
  // (r>>1)&3 == (l16>>1)&3 since wm/wn/16*i are multiples of 16
  const int co = (lg ^ ((l16 >> 1) & 3)) << 4;

  f32x4 acc[4][4];
#pragma unroll
  for (int i = 0; i < 4; i++)
#pragma unroll
    for (int j = 0; j < 4; j++) acc[i][j] = (f32x4)0.f;

  for (int k0 = 0; k0 < K; k0 += 32) {
    if (k0) __syncthreads();
    __builtin_amdgcn_global_load_lds((gp_t)a0, (lp_t)(AsB + dst0), 16, 0, 0);
    __builtin_amdgcn_global_load_lds((gp_t)a1, (lp_t)(AsB + dst1), 16, 0, 0);
    __builtin_amdgcn_global_load_lds((gp_t)b0, (lp_t)(BsB + dst0), 16, 0, 0);
    __builtin_amdgcn_global_load_lds((gp_t)b1, (lp_t)(BsB + dst1), 16, 0, 0);
    a0 += 32; a1 += 32; b0 += 32; b1 += 32;
    __syncthreads();

    bf16x8 af[4], bv[4];
#pragma unroll
    for (int i = 0; i < 4; i++)
      af[i] = *(const bf16x8*)(AsB + (wm + 16 * i + l16) * 64 + co);
#pragma unroll
    for (int j = 0; j < 4; j++)
      bv[j] = *(const bf16x8*)(BsB + (wn + 16 * j + l16) * 64 + co);
#pragma unroll
    for (int i = 0; i < 4; i++)
#pragma unroll
      for (int j = 0; j < 4; j++)
        acc[i][j] = __builtin_amdgcn_mfma_f32_16x16x32_bf16(af[i], bv[j], acc[i][j], 0, 0, 0);
  }

  // epilogue: C/D map col=lane&15, row=(lane>>4)*4+reg
#pragma unroll
  for (int i = 0; i < 4; i++) {
#pragma unroll
    for (int r = 0; r < 4; r++) {
      const int row = m0 + wm + 16 * i + lg * 4 + r;
#pragma unroll
      for (int j = 0; j < 4; j++) {
        const int col = n0 + wn + 16 * j + l16;
        float c = acc[i][j][r];
        if (sg.bias) c += sg.bias[col];
        if (sg.act) c = 0.5f * c * (1.f + erff(c * 0.70710678118654752f));  // exact GELU
        sg.C[(size_t)row * N + col] = f2bf(c);
      }
    }
  }
}

// ------------- select + RoPE -> bf16 Q (prescaled), bf16 K (full token index) -------------
__global__ __launch_bounds__(256) void select_rope_bf(
    const u16* __restrict__ qkv, const u16* __restrict__ qe,
    const u16* __restrict__ ke, u16* __restrict__ Qb, u16* __restrict__ Kb,
    const int* __restrict__ ttm, const int* __restrict__ inv,
    const int* __restrict__ pid)
{
  __shared__ float cs[64], sn[64];
  const int token = blockIdx.x;
  const bool is_e = (ttm[token] == 1);
  const int j = inv[token];
  const int t = threadIdx.x;
  if (t < 64) {
    const float pos = (float)pid[token];
    const float iv = __expf(-((float)(2 * t) * (1.f / 128.f)) * 9.210340371976184f);
    const float f = pos * iv;
    cs[t] = cosf(f); sn[t] = sinf(f);
  }
  __syncthreads();
  const float scale = 0.08838834764831845f;  // 1/sqrt(128) folded into Q
  const u16* qrow = qkv + (size_t)j * 6144;

  for (int it = t; it < H_ * 64; it += 256) {
    const int h = it >> 6, i = it & 63;
    float x1, x2;
    if (is_e) {
      const size_t eb = ((size_t)j * 8 + (h & 7)) * D_;
      x1 = bf2f(qe[eb + i]); x2 = bf2f(qe[eb + i + 64]);
    } else {
      x1 = bf2f(qrow[h * 128 + i]); x2 = bf2f(qrow[h * 128 + i + 64]);
    }
    const size_t base = ((size_t)token * H_ + h) * D_;
    Qb[base + i]      = f2bf((x1 * cs[i] - x2 * sn[i]) * scale);
    Qb[base + i + 64] = f2bf((x2 * cs[i] + x1 * sn[i]) * scale);
  }
  for (int it = t; it < KVH_ * 64; it += 256) {
    const int h = it >> 6, i = it & 63;
    float x1, x2;
    if (is_e) {
      const size_t eb = ((size_t)j * 8 + h) * D_;
      x1 = bf2f(ke[eb + i]); x2 = bf2f(ke[eb + i + 64]);
    } else {
      x1 = bf2f(qrow[4096 + h * 128 + i]); x2 = bf2f(qrow[4096 + h * 128 + i + 64]);
    }
    const size_t base = ((size_t)token * KVH_ + h) * D_;
    Kb[base + i]      = f2bf(x1 * cs[i] - x2 * sn[i]);
    Kb[base + i + 64] = f2bf(x2 * cs[i] + x1 * sn[i]);
  }
}

// ---------- V select + transpose: VT[b][hk][d][s] bf16 ----------
__global__ __launch_bounds__(256) void vtrans_kernel(
    const u16* __restrict__ qkv, const u16* __restrict__ ve,
    const int* __restrict__ ttm, const int* __restrict__ inv,
    u16* __restrict__ VTg)
{
  __shared__ float t[32][33];
  const int dt = blockIdx.x & 3;
  const int st = (blockIdx.x >> 2) & 31;
  const int hk = (blockIdx.x >> 7) & 7;
  const int b  = blockIdx.x >> 10;
  const int s0 = st * 32, d0 = dt * 32;
  const int tx = threadIdx.x & 31, ty = threadIdx.x >> 5;
#pragma unroll
  for (int i = 0; i < 4; i++) {
    const int r = ty + 8 * i;
    const int tok = b * S_ + s0 + r;
    const int j = inv[tok];
    t[r][tx] = (ttm[tok] == 1)
        ? bf2f(ve[((size_t)j * 8 + hk) * D_ + d0 + tx])
        : bf2f(qkv[(size_t)j * 6144 + 5120 + hk * 128 + d0 + tx]);
  }
  __syncthreads();
#pragma unroll
  for (int i = 0; i < 4; i++) {
    const int rr = ty + 8 * i;
    VTg[((size_t)(b * KVH_ + hk) * D_ + d0 + rr) * S_ + s0 + tx] = f2bf(t[tx][rr]);
  }
}

// ------------------- MFMA causal GQA flash attention (compact output) -------------------
// COALESCED STAGING + XOR-swizzled LDS (r7): K/V staging reads contiguous
// rows (16/8 lanes per line); LDS rows are bank-neutral (256B/128B stride
// = 0 mod 32 words) and the chunk XOR balances fragment reads 2-way (free).
__global__ __launch_bounds__(256) void attn_mfma(
    const u16* __restrict__ Qb, const u16* __restrict__ Kb,
    const u16* __restrict__ VTg, u16* __restrict__ O,
    const int* __restrict__ ttm, const int* __restrict__ inv,
    const int* __restrict__ cnt)
{
  __shared__ __align__(16) u16 Ks[64 * 16 * 8];     // [key][chunk^swz][8]
  __shared__ __align__(16) u16 VTs[128 * 8 * 8];    // [d][chunk^swz][8]
  __shared__ __align__(16) float Ps[4][16 * 68];

  const int tid = threadIdx.x;
  const int wave = tid >> 6, lane = tid & 63;
  const int l16 = lane & 15, lg = lane >> 4;

  const int qtile = 15 - (blockIdx.x & 15);
  const int h = (blockIdx.x >> 4) & (H_ - 1);
  const int b = blockIdx.x >> 9;
  const int q0 = qtile * 64;
  const int hk = h & 7;
  const int qw = q0 + 16 * wave;
  const int qmax = qw + 15;

  bf16x8 qf[4];
  {
    const u16* qrow = Qb + ((size_t)(b * S_ + qw + l16) * H_ + h) * D_;
#pragma unroll
    for (int c = 0; c < 4; c++)
      qf[c] = *(const bf16x8*)(qrow + c * 32 + lg * 8);
  }

  f32x4 o[8];
#pragma unroll
  for (int nt = 0; nt < 8; nt++) o[nt] = (f32x4)0.f;
  float mrun[4] = {-1e30f, -1e30f, -1e30f, -1e30f};
  float lrun[4] = {0.f, 0.f, 0.f, 0.f};

  const int ntiles = qtile + 1;
  for (int t = 0; t < ntiles; t++) {
    const int k0 = t * 64;
    if (t) __syncthreads();
    // K stage: coalesced (16 lanes per 256B key-row), swizzled LDS
#pragma unroll
    for (int i = 0; i < 4; i++) {
      const int L = i * 256 + tid;
      const int key = L >> 4, ch = L & 15;
      *(bf16x8*)(Ks + (size_t)key * 128 + ((ch ^ (key & 15)) * 8)) =
          *(const bf16x8*)(Kb + ((size_t)(b * S_ + k0 + key) * KVH_ + hk) * D_ + ch * 8);
    }
    // V stage: coalesced (8 lanes per 128B d-row), swizzled LDS
#pragma unroll
    for (int i = 0; i < 4; i++) {
      const int L = i * 256 + tid;
      const int d = L >> 3, ch = L & 7;
      *(bf16x8*)(VTs + (size_t)d * 64 + ((ch ^ (d & 7)) * 8)) =
          *(const bf16x8*)(VTg + ((size_t)(b * KVH_ + hk) * D_ + d) * S_ + k0 + ch * 8);
    }
    __syncthreads();

    if (k0 > qmax) continue;

    f32x4 s[4];
#pragma unroll
    for (int c = 0; c < 4; c++) s[c] = (f32x4)0.f;
#pragma unroll
    for (int c = 0; c < 4; c++)
#pragma unroll
      for (int dc = 0; dc < 4; dc++) {
        const bf16x8 kf = *(const bf16x8*)(
            Ks + (size_t)(c * 16 + l16) * 128 + (((dc * 4 + lg) ^ l16) * 8));
        s[c] = __builtin_amdgcn_mfma_f32_16x16x32_bf16(qf[dc], kf, s[c], 0, 0, 0);
      }

    float p[4][4], alpha[4];
#pragma unroll
    for (int r = 0; r < 4; r++) {
      const int qg = qw + lg * 4 + r;
      float sv[4], mx = -1e30f;
#pragma unroll
      for (int c = 0; c < 4; c++) {
        const int kg_ = k0 + c * 16 + l16;
        float v = (kg_ <= qg) ? s[c][r] : -1e30f;
        sv[c] = v;
        mx = fmaxf(mx, v);
      }
#pragma unroll
      for (int off = 1; off < 16; off <<= 1)
        mx = fmaxf(mx, __shfl_xor(mx, off));
      const float mn = fmaxf(mrun[r], mx);
      alpha[r] = __expf(mrun[r] - mn);
      mrun[r] = mn;
      float rs = 0.f;
#pragma unroll
      for (int c = 0; c < 4; c++) { p[c][r] = __expf(sv[c] - mn); rs += p[c][r]; }
#pragma unroll
      for (int off = 1; off < 16; off <<= 1)
        rs += __shfl_xor(rs, off);
      lrun[r] = lrun[r] * alpha[r] + rs;
    }
#pragma unroll
    for (int nt = 0; nt < 8; nt++)
#pragma unroll
      for (int r = 0; r < 4; r++) o[nt][r] *= alpha[r];

    float* pw = Ps[wave];
#pragma unroll
    for (int c = 0; c < 4; c++)
#pragma unroll
      for (int r = 0; r < 4; r++)
        pw[(lg * 4 + r) * 68 + c * 16 + l16] = p[c][r];

    bf16x8 pa[2];
#pragma unroll
    for (int kc = 0; kc < 2; kc++) {
      const float* src = pw + l16 * 68 + kc * 32 + lg * 8;
      const float4 f0 = *(const float4*)(src);
      const float4 f1 = *(const float4*)(src + 4);
      bf16x8 v;
      v[0] = (short)f2bf(f0.x); v[1] = (short)f2bf(f0.y);
      v[2] = (short)f2bf(f0.z); v[3] = (short)f2bf(f0.w);
      v[4] = (short)f2bf(f1.x); v[5] = (short)f2bf(f1.y);
      v[6] = (short)f2bf(f1.z); v[7] = (short)f2bf(f1.w);
      pa[kc] = v;
    }

#pragma unroll
    for (int nt = 0; nt < 8; nt++)
#pragma unroll
      for (int kc = 0; kc < 2; kc++) {
        const bf16x8 vf = *(const bf16x8*)(
            VTs + (size_t)(nt * 16 + l16) * 64 + (((kc * 4 + lg) ^ (l16 & 7)) * 8));
        o[nt] = __builtin_amdgcn_mfma_f32_16x16x32_bf16(pa[kc], vf, o[nt], 0, 0, 0);
      }
  }

  // epilogue -> compact row: text j, entity ntext_pad + j
  const int ntext_pad = cnt[1];
#pragma unroll
  for (int r = 0; r < 4; r++) {
    const float inv_l = 1.f / lrun[r];
    const int tok = b * S_ + qw + lg * 4 + r;
    const int j = inv[tok];
    const int crow = (ttm[tok] != 1) ? j : (ntext_pad + j);
    u16* orow = O + (size_t)crow * (H_ * D_) + h * D_ + l16;
#pragma unroll
    for (int nt = 0; nt < 8; nt++)
      orow[nt * 16] = f2bf(o[nt][r] * inv_l);
  }
}

// ------------------- mean over 4 head-replicas (entity-compact) -------------------
__global__ __launch_bounds__(256) void mean_heads_kernel(
    const u16* __restrict__ attn, u16* __restrict__ oe, const int* __restrict__ cnt)
{
  const size_t idx = (size_t)blockIdx.x * 256 + threadIdx.x;
  const int j = (int)(idx >> 10);
  if (j >= cnt[2]) return;
  const int r = (int)(idx & 1023);
  const int h = r >> 7, d = r & 127;
  const u16* a = attn + (size_t)(cnt[1] + j) * (H_ * D_);
  const float s = 0.25f * (bf2f(a[h * D_ + d]) + bf2f(a[(8 + h) * D_ + d]) +
                           bf2f(a[(16 + h) * D_ + d]) + bf2f(a[(24 + h) * D_ + d]));
  oe[idx] = f2bf(s);
}

// ------------------- scatter compact outs -> d_out with type masking -------------------
__global__ __launch_bounds__(256) void scatter_out(
    const u16* __restrict__ ct, const u16* __restrict__ ce,
    const int* __restrict__ ttm, const int* __restrict__ inv,
    float* __restrict__ out_text, float* __restrict__ out_ent)
{
  const int tok = blockIdx.x;
  const bool is_e = (ttm[tok] == 1);
  const int j = inv[tok];
  const int t = threadIdx.x;
  float* ot = out_text + (size_t)tok * HID_;
#pragma unroll
  for (int i = 0; i < 4; i++) {
    const int c = (i * 256 + t) * 4;
    float4 v = make_float4(0.f, 0.f, 0.f, 0.f);
    if (!is_e) {
      const ushort4 u = *(const ushort4*)(ct + (size_t)j * HID_ + c);
      v.x = bf2f(u.x); v.y = bf2f(u.y); v.z = bf2f(u.z); v.w = bf2f(u.w);
    }
    *(float4*)(ot + c) = v;
  }
  float* oe_ = out_ent + (size_t)tok * 1024;
  {
    const int c = t * 4;
    float4 v = make_float4(0.f, 0.f, 0.f, 0.f);
    if (is_e) {
      const ushort4 u = *(const ushort4*)(ce + (size_t)j * 1024 + c);
      v.x = bf2f(u.x); v.y = bf2f(u.y); v.z = bf2f(u.z); v.w = bf2f(u.w);
    }
    *(float4*)(oe_ + c) = v;
  }
}

// ------------------------------- launcher -------------------------------
extern "C" void kernel_launch(void* const* d_in, const int* in_sizes, int n_in,
                              void* d_out, int out_size, void* d_ws, size_t ws_size,
                              hipStream_t stream)
{
  const float* x_text = (const float*)d_in[0];
  const float* x_ent  = (const float*)d_in[1];
  const float* wq_t   = (const float*)d_in[2];
  const float* wk_t   = (const float*)d_in[3];
  const float* wv_t   = (const float*)d_in[4];
  const float* wo_t   = (const float*)d_in[5];
  const float* wq_e   = (const float*)d_in[6];
  const float* wk_e   = (const float*)d_in[7];
  const float* wv_e   = (const float*)d_in[8];
  const float* wo_e   = (const float*)d_in[9];
  const float* aq1_w = (const float*)d_in[10]; const float* aq1_b = (const float*)d_in[11];
  const float* aq2_w = (const float*)d_in[12]; const float* aq2_b = (const float*)d_in[13];
  const float* ak1_w = (const float*)d_in[14]; const float* ak1_b = (const float*)d_in[15];
  const float* ak2_w = (const float*)d_in[16]; const float* ak2_b = (const float*)d_in[17];
  const float* av1_w = (const float*)d_in[18]; const float* av1_b = (const float*)d_in[19];
  const float* av2_w = (const float*)d_in[20]; const float* av2_b = (const float*)d_in[21];
  const float* ao1_w = (const float*)d_in[22]; const float* ao1_b = (const float*)d_in[23];
  const float* ao2_w = (const float*)d_in[24]; const float* ao2_b = (const float*)d_in[25];
  const int*   ttm   = (const int*)d_in[27];
  const int*   pid   = (const int*)d_in[28];

  float* out_text = (float*)d_out;                       // [2048,4096]
  float* out_ent  = out_text + (size_t)B_ * S_ * HID_;   // [2048,1024]

  // ---- workspace layout (bytes), peak ~132.5 MB ----
  // Liveness audit (r4/r5): e_all at 25,165,824 over the qe/ke/ve span.
  // e_all live [batchA.W -> batchB.R]; qe/ke/ve live [batchC.W -> rope/vtrans.R].
  char* w = (char*)d_ws;
  u16*   qkv_bf = (u16*)(w + 0);             // 25,165,824  [2048][6144] compact text
  u16*   e_all  = (u16*)(w + 25165824);      // 12,582,912  [2048][3072] compact ent (batch A-B)
  u16*   qe     = (u16*)(w + 25165824);      //  4,194,304  [2048*8][128] (batch C+)
  u16*   ke     = (u16*)(w + 29360128);      //  4,194,304
  u16*   ve     = (u16*)(w + 33554432);      //  4,194,304
  u16*   h1q    = (u16*)(w + 37748736);      //  8,388,608  [16384][256]
  u16*   attn_bf = (u16*)(w + 0);            // 17,825,792  [2176][4096] compact
  u16*   oe_bf   = (u16*)(w + 17825792);     //  4,194,304
  u16*   h1o     = (u16*)(w + 22020096);     //  8,388,608
  u16*   oe2     = (u16*)(w + 30408704);     //  4,194,304
  u16*   xt_bf = (u16*)(w + 50331648);       // 16,777,216  [2048][4096] compact text
  u16*   Q_bf  = (u16*)(w + 50331648);       // 16,777,216  full-token
  u16*   ct_out = (u16*)(w + 50331648);      // 16,777,216  wo_t compact C
  u16*   h1k   = (u16*)(w + 62914560);       //  8,388,608  (62.9MB..71.3MB)
  u16*   xe_bf = (u16*)(w + 67108864);       //  4,194,304  [2048][1024] compact ent
  u16*   K_bf  = (u16*)(w + 67108864);       //  4,194,304  full-token
  u16*   ce_out = (u16*)(w + 67108864);      //  4,194,304  wo_e compact C
  u16*   WTb   = (u16*)(w + 71303168);       // 50,331,648  [6144][4096]
  u16*   h1v   = (u16*)(w + 71303168);       //  8,388,608  (over dead WTb, pre-WTo)
  u16*   WTo   = (u16*)(w + 71303168);       // 33,554,432  [4096][4096]
  u16*   WTao1 = (u16*)(w + 104857600);      //     65,536
  u16*   WTao2 = (u16*)(w + 104923136);      //     65,536
  u16*   WToe  = (u16*)(w + 104988672);      //  2,097,152
  u16*   WTe   = (u16*)(w + 121634816);      //  6,291,456  [3072][1024]
  u16*   WTa   = (u16*)(w + 127926272);      //    393,216  6 x [.][.]
  u16*   VT_g  = (u16*)(w + 128319488);      //  4,194,304
  int*   inv   = (int*)(w + 132513792);      //      8,192
  int*   cnt   = (int*)(w + 132521984);      //         64

  // batched GEMM launcher: segments padded to %8 blocks
  struct B {
    GArgs ga{}; int blk = 0;
    void add(const u16* A, const u16* Bt, const float* bias, u16* C,
             int M, int N, int K, int act, int astride, int mlimIdx) {
      GSeg& s = ga.s[ga.nseg++];
      s = {A, Bt, bias, C, N, K, act, astride, mlimIdx, blk, M >> 7, N >> 7};
      blk += ((s.nTM * s.nTN) + 7) & ~7;
    }
  };
  auto launch = [&](B& b) {
    gemm_batch<<<dim3(b.blk), dim3(256), 0, stream>>>(b.ga, cnt);
  };

  // weight transposes, batch 1 (everything pre-attention)
  {
    TArgs ta{}; int blk = 0, s = 0;
    auto add = [&](const float* W, u16* Wt, int K, int N) {
      ta.s[s] = {W, Wt, K, N, blk}; blk += (K >> 5) * (N >> 5); s++;
    };
    add(wq_t, WTb, HID_, HID_);
    add(wk_t, WTb + (size_t)4096 * HID_, HID_, 1024);
    add(wv_t, WTb + (size_t)5120 * HID_, HID_, 1024);
    add(wq_e, WTe, 1024, 1024);
    add(wk_e, WTe + (size_t)1024 * 1024, 1024, 1024);
    add(wv_e, WTe + (size_t)2048 * 1024, 1024, 1024);
    add(aq1_w, WTa,          D_, AH_);
    add(aq2_w, WTa + 32768,  AH_, D_);
    add(ak1_w, WTa + 65536,  D_, AH_);
    add(ak2_w, WTa + 98304,  AH_, D_);
    add(av1_w, WTa + 131072, D_, AH_);
    add(av2_w, WTa + 163840, AH_, D_);
    ta.nseg = s;
    batch_transpose<<<dim3(blk), dim3(256), 0, stream>>>(ta);
  }

  // token-type scan + input gather
  build_inv<<<dim3(1), dim3(1024), 0, stream>>>(ttm, inv, cnt);
  gather_cast<<<dim3(NTOK), dim3(256), 0, stream>>>(x_text, x_ent, ttm, inv, xt_bf, xe_bf);

  // batch A: text QKV || entity projection (disjoint regions)
  //   seg0 R:{xt_bf,WTb} W:{qkv_bf}   seg1 R:{xe_bf,WTe} W:{e_all@25.2MB}
  {
    B b;
    b.add(xt_bf, WTb, nullptr, qkv_bf, NTOK, 6144, HID_, 0, 0, 1);
    b.add(xe_bf, WTe, nullptr, e_all, NTOK, 3072, 1024, 0, 0, 3);
    launch(b);
  }
  // batch B: adapter layer-1 q||k||v (share input e_all; outputs disjoint)
  {
    B b;
    b.add(e_all,        WTa,          aq1_b, h1q, NTOK * 8, AH_, D_, 1, 3072, 4);
    b.add(e_all + 1024, WTa + 65536,  ak1_b, h1k, NTOK * 8, AH_, D_, 1, 3072, 4);
    b.add(e_all + 2048, WTa + 131072, av1_b, h1v, NTOK * 8, AH_, D_, 1, 3072, 4);
    launch(b);
  }
  // batch C: adapter layer-2 q||k||v (write qe/ke/ve over dead e_all)
  {
    B b;
    b.add(h1q, WTa + 32768,  aq2_b, qe, NTOK * 8, D_, AH_, 0, 0, 4);
    b.add(h1k, WTa + 98304,  ak2_b, ke, NTOK * 8, D_, AH_, 0, 0, 4);
    b.add(h1v, WTa + 163840, av2_b, ve, NTOK * 8, D_, AH_, 0, 0, 4);
    launch(b);
  }

  // select + RoPE -> full-token Q/K bf16; V transpose
  select_rope_bf<<<dim3(NTOK), dim3(256), 0, stream>>>(
      qkv_bf, qe, ke, Q_bf, K_bf, ttm, inv, pid);
  vtrans_kernel<<<dim3(B_ * KVH_ * 32 * 4), dim3(256), 0, stream>>>(
      qkv_bf, ve, ttm, inv, VT_g);

  // weight transposes, batch 2 (into dead WTb region; h1v already consumed)
  {
    TArgs ta{}; int blk = 0, s = 0;
    auto add = [&](const float* W, u16* Wt, int K, int N) {
      ta.s[s] = {W, Wt, K, N, blk}; blk += (K >> 5) * (N >> 5); s++;
    };
    add(wo_t, WTo, HID_, HID_);
    add(ao1_w, WTao1, D_, AH_);
    add(ao2_w, WTao2, AH_, D_);
    add(wo_e, WToe, 1024, 1024);
    ta.nseg = s;
    batch_transpose<<<dim3(blk), dim3(256), 0, stream>>>(ta);
  }

  // MFMA flash attention -> compact bf16 (text rows [0,ntext), entity at ntext_pad)
  attn_mfma<<<dim3(B_ * H_ * 16), dim3(256), 0, stream>>>(
      Q_bf, K_bf, VT_g, attn_bf, ttm, inv, cnt);

  // entity mean, then batch D: wo_t || adapter-out layer-1 (disjoint regions)
  //   seg0 R:{attn_bf 0-17.8M, WTo} W:{ct_out 50.3-67.1M}
  //   seg1 R:{oe_bf 17.8-22.0M, WTao1} W:{h1o 22.0-30.4M}
  mean_heads_kernel<<<dim3(NTOK * 1024 / 256), dim3(256), 0, stream>>>(attn_bf, oe_bf, cnt);
  {
    B b;
    b.add(attn_bf, WTo, nullptr, ct_out, NTOK, HID_, HID_, 0, 0, 1);
    b.add(oe_bf, WTao1, ao1_b, h1o, NTOK * 8, AH_, D_, 1, 0, 4);
    launch(b);
  }
  // serial tail of entity chain
  {
    B b; b.add(h1o, WTao2, ao2_b, oe2, NTOK * 8, D_, AH_, 0, 0, 4); launch(b);
  }
  {
    B b; b.add(oe2, WToe, nullptr, ce_out, NTOK, 1024, 1024, 0, 0, 3); launch(b);
  }

  // scatter to d_out with type masking
  scatter_out<<<dim3(NTOK), dim3(256), 0, stream>>>(
      ct_out, ce_out, ttm, inv, out_text, out_ent);
}